// Round 1
// baseline (1782.893 us; speedup 1.0000x reference)
//
#include <hip/hip_runtime.h>
#include <cmath>

// ---------------------------------------------------------------------------
// MHA forward, fp32 baseline.
//   x:[B,S,D] @ Wq/Wk/Wv -> Q,K,V in head layout [B,H,S,dk]
//   RoPE(Q), RoPE(K) (interleaved pairs)
//   causal flash attention per (b,h) -> AO [B,S,D]
//   AO @ Wo -> out
// B=2 S=2048 D=1024 H=16 dk=64
// ---------------------------------------------------------------------------

constexpr int Bz = 2, Sq = 2048, Dm = 1024, Hh = 16, DK = 64;
constexpr int Mrows = Bz * Sq;                 // 4096
constexpr int NHEAD_ELEMS = Bz * Hh * Sq * DK; // 4,194,304 elements (16 MB fp32)

// ============================ GEMM (fp32) ==================================
// C[M,N] = A[M,K] @ W[K,N], M=4096, N=K=1024. 128x128 tile, 8x8 per thread.
constexpr int BM = 128, BN = 128, BK = 16;

template <bool HEADOUT>
__device__ __forceinline__ void gemm_store(float* C, int m, int n, const float4& v) {
  if (HEADOUT) {
    // row m = b*S+s ; col n = h*64+d  ->  C[((b*H+h)*S+s)*64 + d]
    int b = m >> 11, s = m & (Sq - 1);
    int h = n >> 6, d = n & 63;
    *(float4*)&C[(((size_t)(b * Hh + h) * Sq) + s) * DK + d] = v;
  } else {
    *(float4*)&C[(size_t)m * Dm + n] = v;
  }
}

template <bool HEADOUT>
__device__ __forceinline__ void gemm_core(const float* __restrict__ A,
                                          const float* __restrict__ W,
                                          float* __restrict__ C) {
  __shared__ float As[BK][BM + 4];        // A tile, stored transposed [k][m]
  __shared__ float WsA[BK][BN / 2 + 4];   // W cols with (c>>2) even  (b0 half)
  __shared__ float WsB[BK][BN / 2 + 4];   // W cols with (c>>2) odd   (b1 half)

  const int tid = threadIdx.x;
  const int tx = tid & 15, ty = tid >> 4;
  const int m0 = blockIdx.y * BM, n0 = blockIdx.x * BN;

  float acc[8][8];
#pragma unroll
  for (int i = 0; i < 8; ++i)
#pragma unroll
    for (int j = 0; j < 8; ++j) acc[i][j] = 0.f;

  for (int k0 = 0; k0 < Dm; k0 += BK) {
    // A tile 128x16 -> 512 float4, 2 per thread
#pragma unroll
    for (int f = tid; f < 512; f += 256) {
      int r = f >> 2, kq = (f & 3) << 2;
      float4 v = *(const float4*)&A[(size_t)(m0 + r) * Dm + k0 + kq];
      As[kq + 0][r] = v.x; As[kq + 1][r] = v.y;
      As[kq + 2][r] = v.z; As[kq + 3][r] = v.w;
    }
    // W tile 16x128 -> 512 float4, 2 per thread; split even/odd float4 columns
#pragma unroll
    for (int f = tid; f < 512; f += 256) {
      int r = f >> 5, c4 = f & 31;
      float4 v = *(const float4*)&W[(size_t)(k0 + r) * Dm + n0 + (c4 << 2)];
      if (c4 & 1) *(float4*)&WsB[r][(c4 >> 1) << 2] = v;
      else        *(float4*)&WsA[r][(c4 >> 1) << 2] = v;
    }
    __syncthreads();

#pragma unroll
    for (int k = 0; k < BK; ++k) {
      float4 a0 = *(float4*)&As[k][ty * 8];
      float4 a1 = *(float4*)&As[k][ty * 8 + 4];
      float4 b0 = *(float4*)&WsA[k][tx * 4];  // cols tx*8 .. +3
      float4 b1 = *(float4*)&WsB[k][tx * 4];  // cols tx*8+4 .. +7
      float a[8] = {a0.x, a0.y, a0.z, a0.w, a1.x, a1.y, a1.z, a1.w};
      float bb[8] = {b0.x, b0.y, b0.z, b0.w, b1.x, b1.y, b1.z, b1.w};
#pragma unroll
      for (int i = 0; i < 8; ++i)
#pragma unroll
        for (int j = 0; j < 8; ++j) acc[i][j] = fmaf(a[i], bb[j], acc[i][j]);
    }
    __syncthreads();
  }

#pragma unroll
  for (int i = 0; i < 8; ++i) {
    int m = m0 + ty * 8 + i;
    float4 v0 = {acc[i][0], acc[i][1], acc[i][2], acc[i][3]};
    float4 v1 = {acc[i][4], acc[i][5], acc[i][6], acc[i][7]};
    gemm_store<HEADOUT>(C, m, n0 + tx * 8, v0);
    gemm_store<HEADOUT>(C, m, n0 + tx * 8 + 4, v1);
  }
}

__global__ __launch_bounds__(256) void gemm_qkv_kernel(
    const float* __restrict__ x, const float* __restrict__ Wq,
    const float* __restrict__ Wk, const float* __restrict__ Wv,
    float* __restrict__ Qh, float* __restrict__ Kh, float* __restrict__ Vh) {
  int z = blockIdx.z;
  const float* W = (z == 0) ? Wq : (z == 1) ? Wk : Wv;
  float* C = (z == 0) ? Qh : (z == 1) ? Kh : Vh;
  gemm_core<true>(x, W, C);
}

__global__ __launch_bounds__(256) void gemm_o_kernel(
    const float* __restrict__ A, const float* __restrict__ Wo,
    float* __restrict__ C) {
  gemm_core<false>(A, Wo, C);
}

// ============================ RoPE (in-place) ===============================
// head layout [B,H,S,dk]; pairs (2j,2j+1), theta = s * 10000^(-j/32)
__global__ __launch_bounds__(256) void rope_kernel(float* __restrict__ Qh,
                                                   float* __restrict__ Kh) {
  int t = blockIdx.x * 256 + threadIdx.x;   // 0 .. 2*2^21-1
  int tensor = t >> 21;                     // pairs per tensor = 2^21
  int p = t & ((1 << 21) - 1);
  int row = p >> 5, j = p & 31;
  int s = row & (Sq - 1);
  float inv = 1.0f / powf(10000.0f, (float)j * (1.0f / 32.0f));
  float th = (float)s * inv;
  float sn, cs;
  sincosf(th, &sn, &cs);
  float* base = tensor ? Kh : Qh;
  float2* ptr = (float2*)(base + (size_t)row * DK) + j;
  float2 v = *ptr;
  *ptr = make_float2(v.x * cs - v.y * sn, v.y * cs + v.x * sn);
}

// ======================= Flash attention (fp32) =============================
// block = 256 thr (4 waves), 32 q-rows/block, 64-k tiles, online softmax.
// lane -> (k2 = lane&31 covers k/d pair, qh = lane>>5), wave -> 8 q rows.
__global__ __launch_bounds__(256) void attn_kernel(
    const float* __restrict__ Qh, const float* __restrict__ Kh,
    const float* __restrict__ Vh, float* __restrict__ AO) {
  constexpr int R = 32, TK = 64;
  constexpr int NQ = Sq / R;  // 64

  int bid = blockIdx.x;
  int qblk = (NQ - 1) - (bid % NQ);  // big-q first for load balance
  int bh = bid / NQ;
  int b = bh >> 4, h = bh & 15;
  int q0 = qblk * R;

  const float4* Qp4 = (const float4*)(Qh + (size_t)bh * Sq * DK);
  const float4* Kp4 = (const float4*)(Kh + (size_t)bh * Sq * DK);
  const float4* Vp4 = (const float4*)(Vh + (size_t)bh * Sq * DK);

  __shared__ float4 Qs4[R * 16];   // 8 KB  [r][d4]
  __shared__ float4 Ks4[TK * 16];  // 16 KB swizzled: slot = k*16 + (d4 ^ ((k>>1)&7))
  __shared__ float4 Vs4[TK * 16];  // 16 KB linear   [k][d4]
  __shared__ float Ps[R][TK];      // 8 KB

  const int tid = threadIdx.x;
  const int lane = tid & 63, wave = tid >> 6;
  const int k2 = lane & 31, qh = lane >> 5;
  const int qbase = wave * 8 + qh * 4;  // this lane's 4 local q rows

  for (int f = tid; f < R * 16; f += 256)
    Qs4[f] = Qp4[(q0 + (f >> 4)) * 16 + (f & 15)];

  float out_[4][2], m_[4], l_[4];
#pragma unroll
  for (int i = 0; i < 4; ++i) {
    out_[i][0] = out_[i][1] = 0.f;
    m_[i] = -1e30f;
    l_[i] = 0.f;
  }

  const int nt = (q0 + R - 1) / TK + 1;
  for (int kt = 0; kt < nt; ++kt) {
    __syncthreads();  // prev PV done (and Qs staged, iter 0) before restage
    for (int f = tid; f < TK * 16; f += 256) {
      int k = f >> 4, d4 = f & 15;
      Ks4[k * 16 + (d4 ^ ((k >> 1) & 7))] = Kp4[(kt * TK + k) * 16 + d4];
      Vs4[f] = Vp4[(kt * TK + k) * 16 + d4];
    }
    __syncthreads();

    // ---- scores: s[i][kk] = Q[row i] . K[2*k2+kk] ----
    float s_[4][2];
#pragma unroll
    for (int i = 0; i < 4; ++i) s_[i][0] = s_[i][1] = 0.f;
#pragma unroll
    for (int d4 = 0; d4 < 16; ++d4) {
      float4 kva = Ks4[(2 * k2 + 0) * 16 + (d4 ^ (k2 & 7))];
      float4 kvb = Ks4[(2 * k2 + 1) * 16 + (d4 ^ (k2 & 7))];
#pragma unroll
      for (int i = 0; i < 4; ++i) {
        float4 q4 = Qs4[(qbase + i) * 16 + d4];
        s_[i][0] += q4.x * kva.x + q4.y * kva.y + q4.z * kva.z + q4.w * kva.w;
        s_[i][1] += q4.x * kvb.x + q4.y * kvb.y + q4.z * kvb.z + q4.w * kvb.w;
      }
    }

    // ---- mask + online softmax (32-lane row groups) ----
    float corr_[4];
#pragma unroll
    for (int i = 0; i < 4; ++i) {
      int qg = q0 + qbase + i;
      int kg = kt * TK + 2 * k2;
      float sa = (kg + 0 <= qg) ? s_[i][0] * 0.125f : -1e30f;
      float sb = (kg + 1 <= qg) ? s_[i][1] * 0.125f : -1e30f;
      float mt = fmaxf(sa, sb);
#pragma unroll
      for (int off = 16; off >= 1; off >>= 1) mt = fmaxf(mt, __shfl_xor(mt, off));
      float mnew = fmaxf(m_[i], mt);
      float corr = __expf(m_[i] - mnew);
      float p0 = __expf(sa - mnew), p1 = __expf(sb - mnew);
      float ls = p0 + p1;
#pragma unroll
      for (int off = 16; off >= 1; off >>= 1) ls += __shfl_xor(ls, off);
      l_[i] = l_[i] * corr + ls;
      m_[i] = mnew;
      corr_[i] = corr;
      *(float2*)&Ps[qbase + i][2 * k2] = make_float2(p0, p1);
    }
    __syncthreads();

    // ---- PV: out[i][c] += sum_k P[i][k] * V[k][2*k2+c] ----
#pragma unroll
    for (int i = 0; i < 4; ++i) {
      out_[i][0] *= corr_[i];
      out_[i][1] *= corr_[i];
    }
    const float2* Vs2 = (const float2*)Vs4;
#pragma unroll 4
    for (int kp = 0; kp < 32; ++kp) {
      float2 va = Vs2[(2 * kp + 0) * 32 + k2];
      float2 vb = Vs2[(2 * kp + 1) * 32 + k2];
#pragma unroll
      for (int i = 0; i < 4; ++i) {
        float2 p2 = *(const float2*)&Ps[qbase + i][2 * kp];
        out_[i][0] += p2.x * va.x + p2.y * vb.x;
        out_[i][1] += p2.x * va.y + p2.y * vb.y;
      }
    }
  }

#pragma unroll
  for (int i = 0; i < 4; ++i) {
    int qg = q0 + qbase + i;
    float inv = 1.0f / l_[i];
    *(float2*)&AO[((size_t)(b * Sq) + qg) * Dm + h * DK + 2 * k2] =
        make_float2(out_[i][0] * inv, out_[i][1] * inv);
  }
}

// ================================ launch ===================================
extern "C" void kernel_launch(void* const* d_in, const int* in_sizes, int n_in,
                              void* d_out, int out_size, void* d_ws,
                              size_t ws_size, hipStream_t stream) {
  const float* x  = (const float*)d_in[0];
  const float* Wq = (const float*)d_in[1];
  const float* Wk = (const float*)d_in[2];
  const float* Wv = (const float*)d_in[3];
  const float* Wo = (const float*)d_in[4];
  float* out = (float*)d_out;

  float* Qh = (float*)d_ws;            // [B,H,S,dk] 16 MB
  float* Kh = Qh + NHEAD_ELEMS;        // 16 MB
  float* Vh = Kh + NHEAD_ELEMS;        // 16 MB
  float* AO = Vh + NHEAD_ELEMS;        // [B,S,D]   16 MB

  gemm_qkv_kernel<<<dim3(Dm / BN, Mrows / BM, 3), 256, 0, stream>>>(
      x, Wq, Wk, Wv, Qh, Kh, Vh);
  rope_kernel<<<(2 * (NHEAD_ELEMS / 2)) / 256, 256, 0, stream>>>(Qh, Kh);
  attn_kernel<<<Bz * Hh * (Sq / 32), 256, 0, stream>>>(Qh, Kh, Vh, AO);
  gemm_o_kernel<<<dim3(Dm / BN, Mrows / BM), 256, 0, stream>>>(AO, Wo, out);
}

// Round 2
// 916.444 us; speedup vs baseline: 1.9454x; 1.9454x over previous
//
#include <hip/hip_runtime.h>
#include <cmath>

// ---------------------------------------------------------------------------
// MHA forward. fp32 GEMM cores; bf16 MFMA flash attention.
//   gemm<0>: x@Wq -> RoPE -> Qb bf16 [bh][s][64]
//   gemm<0>: x@Wk -> RoPE -> Kb bf16 [bh][s][64]
//   gemm<1>: x@Wv -> Vt bf16 [bh][64][s]   (transposed for MFMA B-operand)
//   attn:    causal flash attention (mfma_f32_16x16x32_bf16) -> AO fp32 [B,S,D]
//   gemm<2>: AO@Wo -> out fp32
// B=2 S=2048 D=1024 H=16 dk=64
// ---------------------------------------------------------------------------

constexpr int Bz = 2, Sq = 2048, Dm = 1024, Hh = 16, DK = 64;
constexpr int Mrows = Bz * Sq;  // 4096

typedef __attribute__((ext_vector_type(4))) float f32x4;
typedef __attribute__((ext_vector_type(8))) __bf16 bf16x8;
typedef __attribute__((ext_vector_type(8))) short short8;

__device__ __forceinline__ f32x4 mfma16(bf16x8 a, bf16x8 b, f32x4 c) {
  return __builtin_amdgcn_mfma_f32_16x16x32_bf16(a, b, c, 0, 0, 0);
}

__device__ __forceinline__ short f2bf(float x) {
  union { float f; unsigned u; } v;
  v.f = x;
  unsigned r = v.u + 0x7fff + ((v.u >> 16) & 1);  // RNE
  return (short)(r >> 16);
}

// ============================ GEMM (fp32 core) ==============================
// C[M,N] = A[M,K] @ W[K,N], M=4096, N=K=1024. 128x128 tile, 8x8 per thread.
// MODE 0: head-layout bf16 + fused RoPE (Q,K).  MODE 1: transposed bf16 (V).
// MODE 2: flat fp32.
constexpr int BM = 128, BN = 128, BK = 16;

template <int MODE>
__global__ __launch_bounds__(256) void gemm_kernel(const float* __restrict__ A,
                                                   const float* __restrict__ W,
                                                   void* __restrict__ Cout) {
  __shared__ float As[BK][BM + 4];
  __shared__ float WsA[BK][BN / 2 + 4];
  __shared__ float WsB[BK][BN / 2 + 4];

  const int tid = threadIdx.x;
  const int tx = tid & 15, ty = tid >> 4;
  const int m0 = blockIdx.y * BM, n0 = blockIdx.x * BN;

  float acc[8][8];
#pragma unroll
  for (int i = 0; i < 8; ++i)
#pragma unroll
    for (int j = 0; j < 8; ++j) acc[i][j] = 0.f;

  for (int k0 = 0; k0 < Dm; k0 += BK) {
#pragma unroll
    for (int f = tid; f < 512; f += 256) {
      int r = f >> 2, kq = (f & 3) << 2;
      float4 v = *(const float4*)&A[(size_t)(m0 + r) * Dm + k0 + kq];
      As[kq + 0][r] = v.x; As[kq + 1][r] = v.y;
      As[kq + 2][r] = v.z; As[kq + 3][r] = v.w;
    }
#pragma unroll
    for (int f = tid; f < 512; f += 256) {
      int r = f >> 5, c4 = f & 31;
      float4 v = *(const float4*)&W[(size_t)(k0 + r) * Dm + n0 + (c4 << 2)];
      if (c4 & 1) *(float4*)&WsB[r][(c4 >> 1) << 2] = v;
      else        *(float4*)&WsA[r][(c4 >> 1) << 2] = v;
    }
    __syncthreads();

#pragma unroll
    for (int k = 0; k < BK; ++k) {
      float4 a0 = *(float4*)&As[k][ty * 8];
      float4 a1 = *(float4*)&As[k][ty * 8 + 4];
      float4 b0 = *(float4*)&WsA[k][tx * 4];
      float4 b1 = *(float4*)&WsB[k][tx * 4];
      float a[8] = {a0.x, a0.y, a0.z, a0.w, a1.x, a1.y, a1.z, a1.w};
      float bb[8] = {b0.x, b0.y, b0.z, b0.w, b1.x, b1.y, b1.z, b1.w};
#pragma unroll
      for (int i = 0; i < 8; ++i)
#pragma unroll
        for (int j = 0; j < 8; ++j) acc[i][j] = fmaf(a[i], bb[j], acc[i][j]);
    }
    __syncthreads();
  }

  if (MODE == 2) {
    float* C = (float*)Cout;
#pragma unroll
    for (int i = 0; i < 8; ++i) {
      int m = m0 + ty * 8 + i;
      float4 v0 = {acc[i][0], acc[i][1], acc[i][2], acc[i][3]};
      float4 v1 = {acc[i][4], acc[i][5], acc[i][6], acc[i][7]};
      *(float4*)&C[(size_t)m * Dm + n0 + tx * 8] = v0;
      *(float4*)&C[(size_t)m * Dm + n0 + tx * 8 + 4] = v1;
    }
  } else if (MODE == 0) {
    // head layout [bh][s][64], bf16, fused interleaved RoPE
    __bf16* C = (__bf16*)Cout;
    const int n = n0 + tx * 8;
    const int h = (n >> 6) & (Hh - 1);
    const int dcol = n & (DK - 1);
    float invf[4];
#pragma unroll
    for (int p = 0; p < 4; ++p)
      invf[p] = exp2f(-0.4152410118609203f * (float)((dcol >> 1) + p));
#pragma unroll
    for (int i = 0; i < 8; ++i) {
      int m = m0 + ty * 8 + i;
      int b = m >> 11, s = m & (Sq - 1);
      short8 pk;
#pragma unroll
      for (int p = 0; p < 4; ++p) {
        float sn, cs;
        sincosf((float)s * invf[p], &sn, &cs);
        float x = acc[i][2 * p], y = acc[i][2 * p + 1];
        pk[2 * p]     = f2bf(x * cs - y * sn);
        pk[2 * p + 1] = f2bf(y * cs + x * sn);
      }
      *(short8*)&C[(((size_t)(b * Hh + h) * Sq) + s) * DK + dcol] = pk;
    }
  } else {  // MODE 1: V transposed [bh][d][s], bf16
    __bf16* C = (__bf16*)Cout;
    const int n = n0 + tx * 8;
    const int h = (n >> 6) & (Hh - 1);
    const int d0 = n & (DK - 1);
    const int b = m0 >> 11;
    const int srow = (m0 & (Sq - 1)) + ty * 8;
#pragma unroll
    for (int jc = 0; jc < 8; ++jc) {
      short8 pk;
#pragma unroll
      for (int i = 0; i < 8; ++i) pk[i] = f2bf(acc[i][jc]);
      *(short8*)&C[((size_t)(b * Hh + h) * DK + d0 + jc) * Sq + srow] = pk;
    }
  }
}

// ======================= Flash attention (bf16 MFMA) ========================
// 256 thr = 4 waves; block -> (bh, 64-row q-chunk); wave -> 16 q-rows.
// Swapped QK^T: S^T = K.Q^T so softmax row lives on lane (col=q).
// P exchanged via wave-private XOR-swizzled LDS (write b64, read b128).
// K from global row-major [s][64]; V from global transposed [d][s].
__global__ __launch_bounds__(256) void attn_kernel(
    const __bf16* __restrict__ Qb, const __bf16* __restrict__ Kb,
    const __bf16* __restrict__ Vt, float* __restrict__ AO) {
  __shared__ __align__(16) char Plds[4][2048];

  const int bid = blockIdx.x;
  const int qc = 31 - (bid & 31);  // big q first
  const int bh = bid >> 5;
  const int b = bh >> 4, h = bh & (Hh - 1);
  const int tid = threadIdx.x, lane = tid & 63, wave = tid >> 6;
  const int g = lane >> 4, qi = lane & 15;
  const int q0w = qc * 64 + wave * 16;

  const __bf16* Qp = Qb + (size_t)bh * Sq * DK;
  const __bf16* Kp = Kb + (size_t)bh * Sq * DK;
  const __bf16* Vp = Vt + (size_t)bh * DK * Sq;

  // Q fragments: B-operand, lane holds Q[q0w+qi][8g+e (+32c)]
  const bf16x8 qf0 = *(const bf16x8*)(Qp + (q0w + qi) * DK + 8 * g);
  const bf16x8 qf1 = *(const bf16x8*)(Qp + (q0w + qi) * DK + 32 + 8 * g);

  f32x4 acc[4];
#pragma unroll
  for (int j = 0; j < 4; ++j) acc[j] = (f32x4){0.f, 0.f, 0.f, 0.f};
  float m_ = -1e30f, l_ = 0.f;

  char* myP = (char*)Plds[wave];
  const int swz = (qi & 7) << 4;
  const int nt = qc + 1;

  for (int kt = 0; kt < nt; ++kt) {
    const int kbase = kt * 64;

    bf16x8 kf[4][2];
#pragma unroll
    for (int bb = 0; bb < 4; ++bb) {
      const __bf16* kr = Kp + (kbase + 16 * bb + qi) * DK + 8 * g;
      kf[bb][0] = *(const bf16x8*)kr;
      kf[bb][1] = *(const bf16x8*)(kr + 32);
    }
    bf16x8 vf[4][2];
#pragma unroll
    for (int j = 0; j < 4; ++j) {
      const __bf16* vr = Vp + (16 * j + qi) * Sq + kbase + 8 * g;
      vf[j][0] = *(const bf16x8*)vr;
      vf[j][1] = *(const bf16x8*)(vr + 32);
    }

    // S^T blocks: D[k=16bb+4g+r][q=qi]
    f32x4 st[4];
#pragma unroll
    for (int bb = 0; bb < 4; ++bb) {
      st[bb] = mfma16(kf[bb][0], qf0, (f32x4){0.f, 0.f, 0.f, 0.f});
      st[bb] = mfma16(kf[bb][1], qf1, st[bb]);
    }

    // scale + causal mask (only the diagonal tile needs masking)
    float sv[4][4];
    float tmax = -1e30f;
    const bool maskt = (kt == qc);
#pragma unroll
    for (int bb = 0; bb < 4; ++bb)
#pragma unroll
      for (int r = 0; r < 4; ++r) {
        float v = st[bb][r] * 0.125f;
        if (maskt && (kbase + 16 * bb + 4 * g + r > q0w + qi)) v = -1e30f;
        sv[bb][r] = v;
        tmax = fmaxf(tmax, v);
      }
    tmax = fmaxf(tmax, __shfl_xor(tmax, 16));
    tmax = fmaxf(tmax, __shfl_xor(tmax, 32));
    const float mnew = fmaxf(m_, tmax);
    const float corr = __expf(m_ - mnew);
    float ls = 0.f;
    unsigned int pw[4][2];
#pragma unroll
    for (int bb = 0; bb < 4; ++bb) {
      float p0 = __expf(sv[bb][0] - mnew), p1 = __expf(sv[bb][1] - mnew);
      float p2 = __expf(sv[bb][2] - mnew), p3 = __expf(sv[bb][3] - mnew);
      ls += (p0 + p1) + (p2 + p3);
      pw[bb][0] = (unsigned int)(unsigned short)f2bf(p0) |
                  ((unsigned int)(unsigned short)f2bf(p1) << 16);
      pw[bb][1] = (unsigned int)(unsigned short)f2bf(p2) |
                  ((unsigned int)(unsigned short)f2bf(p3) << 16);
    }
    ls += __shfl_xor(ls, 16);
    ls += __shfl_xor(ls, 32);
    l_ = l_ * corr + ls;
    m_ = mnew;

    // P[q=qi][k=16bb+4g+r] -> LDS at row qi, byte (2k) ^ swz
#pragma unroll
    for (int bb = 0; bb < 4; ++bb)
      *(uint2*)(myP + qi * 128 + ((32 * bb + 8 * g) ^ swz)) =
          make_uint2(pw[bb][0], pw[bb][1]);

    // rescale accumulators (rows q=4g+r need corr from lane qi==4g+r)
    float cr[4];
#pragma unroll
    for (int r = 0; r < 4; ++r) cr[r] = __shfl(corr, 4 * g + r);
#pragma unroll
    for (int j = 0; j < 4; ++j) {
      acc[j][0] *= cr[0]; acc[j][1] *= cr[1];
      acc[j][2] *= cr[2]; acc[j][3] *= cr[3];
    }

    // P fragments: A-operand, lane reads P[qi][32c+8g+e]
    bf16x8 pa0 = *(bf16x8*)(myP + qi * 128 + ((16 * g) ^ swz));
    bf16x8 pa1 = *(bf16x8*)(myP + qi * 128 + ((64 + 16 * g) ^ swz));
#pragma unroll
    for (int j = 0; j < 4; ++j) {
      acc[j] = mfma16(pa0, vf[j][0], acc[j]);
      acc[j] = mfma16(pa1, vf[j][1], acc[j]);
    }
  }

  const float inv = 1.f / l_;
  float ir[4];
#pragma unroll
  for (int r = 0; r < 4; ++r) ir[r] = __shfl(inv, 4 * g + r);
#pragma unroll
  for (int j = 0; j < 4; ++j)
#pragma unroll
    for (int r = 0; r < 4; ++r)
      AO[((size_t)b * Sq + q0w + 4 * g + r) * Dm + h * DK + 16 * j + qi] =
          acc[j][r] * ir[r];
}

// ================================ launch ===================================
extern "C" void kernel_launch(void* const* d_in, const int* in_sizes, int n_in,
                              void* d_out, int out_size, void* d_ws,
                              size_t ws_size, hipStream_t stream) {
  const float* x  = (const float*)d_in[0];
  const float* Wq = (const float*)d_in[1];
  const float* Wk = (const float*)d_in[2];
  const float* Wv = (const float*)d_in[3];
  const float* Wo = (const float*)d_in[4];
  float* out = (float*)d_out;

  char* w = (char*)d_ws;
  __bf16* Qb = (__bf16*)(w);                       // 8 MB [bh][s][64]
  __bf16* Kb = (__bf16*)(w + (8u << 20));          // 8 MB [bh][s][64]
  __bf16* Vt = (__bf16*)(w + (16u << 20));         // 8 MB [bh][64][s]
  float*  AO = (float*)(w + (24u << 20));          // 16 MB [B,S,D]

  dim3 gg(Dm / BN, Mrows / BM);
  gemm_kernel<0><<<gg, 256, 0, stream>>>(x, Wq, (void*)Qb);
  gemm_kernel<0><<<gg, 256, 0, stream>>>(x, Wk, (void*)Kb);
  gemm_kernel<1><<<gg, 256, 0, stream>>>(x, Wv, (void*)Vt);
  attn_kernel<<<Bz * Hh * (Sq / 64), 256, 0, stream>>>(Qb, Kb, Vt, AO);
  gemm_kernel<2><<<gg, 256, 0, stream>>>(AO, Wo, (void*)out);
}

// Round 3
// 347.722 us; speedup vs baseline: 5.1273x; 2.6356x over previous
//
#include <hip/hip_runtime.h>
#include <cmath>

// ---------------------------------------------------------------------------
// MHA forward, bf16-MFMA everywhere.
//   prep:  x->bf16 ; Wq/Wk/Wv/Wo -> bf16 transposed [n][k] ; RoPE table
//   gemm<0>: xb@Wt -> RoPE -> Qb/Kb bf16 [bh][s][64]
//   gemm<1>: xb@Wt -> Vt bf16 [bh][64][s]  (LDS-transposed epilogue)
//   attn:    causal flash attention (mfma 16x16x32 bf16) -> AOb bf16 [B,S,D]
//   gemm<2>: AOb@Wto -> out fp32
// B=2 S=2048 D=1024 H=16 dk=64
// ---------------------------------------------------------------------------

constexpr int Bz = 2, Sq = 2048, Dm = 1024, Hh = 16, DK = 64;
constexpr int Mrows = Bz * Sq;  // 4096

typedef __attribute__((ext_vector_type(4))) float f32x4;
typedef __attribute__((ext_vector_type(8))) __bf16 bf16x8;
typedef __attribute__((ext_vector_type(4))) short short4v;
typedef __attribute__((ext_vector_type(8))) short short8v;

__device__ __forceinline__ f32x4 mfma16(bf16x8 a, bf16x8 b, f32x4 c) {
  return __builtin_amdgcn_mfma_f32_16x16x32_bf16(a, b, c, 0, 0, 0);
}
__device__ __forceinline__ short f2bf(float x) {
  union { float f; unsigned u; } v;
  v.f = x;
  unsigned r = v.u + 0x7fff + ((v.u >> 16) & 1);  // RNE
  return (short)(r >> 16);
}
// async global->LDS, 16 B per lane; lds ptr must be wave-uniform
__device__ __forceinline__ void gload16(const void* g, void* l) {
  __builtin_amdgcn_global_load_lds(
      (__attribute__((address_space(1))) void*)g,
      (__attribute__((address_space(3))) void*)l, 16, 0, 0);
}

// ============================ prep kernels =================================
__global__ __launch_bounds__(256) void conv_x_kernel(
    const float* __restrict__ in, __bf16* __restrict__ outb) {
  int t = blockIdx.x * 256 + threadIdx.x;  // 524288 threads, 8 elems each
  const float4* p = (const float4*)in + (size_t)t * 2;
  float4 a = p[0], b = p[1];
  short8v o = {f2bf(a.x), f2bf(a.y), f2bf(a.z), f2bf(a.w),
               f2bf(b.x), f2bf(b.y), f2bf(b.z), f2bf(b.w)};
  *(short8v*)((short*)outb + (size_t)t * 8) = o;
}

// W[k][n] fp32 -> Wt[n][k] bf16, 4 tensors
__global__ __launch_bounds__(256) void conv_wt_kernel(
    const float* __restrict__ Wq, const float* __restrict__ Wk,
    const float* __restrict__ Wv, const float* __restrict__ Wo,
    __bf16* __restrict__ outb) {
  __shared__ float tile[32][33];
  int z = blockIdx.z;
  const float* W = (z == 0) ? Wq : (z == 1) ? Wk : (z == 2) ? Wv : Wo;
  short* out = (short*)outb + (size_t)z * Dm * Dm;
  int r0 = blockIdx.y * 32, c0 = blockIdx.x * 32;
  int t = threadIdx.x;
  int r = t >> 3, c4 = (t & 7) * 4;
  float4 v = *(const float4*)&W[(size_t)(r0 + r) * Dm + c0 + c4];
  tile[r][c4] = v.x; tile[r][c4 + 1] = v.y;
  tile[r][c4 + 2] = v.z; tile[r][c4 + 3] = v.w;
  __syncthreads();
  int nl = t >> 3, k4 = (t & 7) * 4;
  short4v o = {f2bf(tile[k4][nl]), f2bf(tile[k4 + 1][nl]),
               f2bf(tile[k4 + 2][nl]), f2bf(tile[k4 + 3][nl])};
  *(short4v*)&out[(size_t)(c0 + nl) * Dm + r0 + k4] = o;
}

// tbl[s][j] = (cos, sin)(s * 10000^(-j/32)), s<2048, j<32
__global__ __launch_bounds__(256) void rope_tbl_kernel(float2* __restrict__ tbl) {
  int t = blockIdx.x * 256 + threadIdx.x;  // 65536
  int s = t >> 5, j = t & 31;
  float inv = exp2f(-13.287712379549449f * (1.0f / 32.0f) * (float)j);
  float sn, cs;
  sincosf((float)s * inv, &sn, &cs);
  tbl[t] = make_float2(cs, sn);
}

// ========================= bf16 MFMA GEMM ==================================
// C[4096][1024] = A[4096][1024] @ Bt[n][k]^T. 128x128 tile, BK=32, 4 waves.
// MODE 0: RoPE epilogue -> head-layout bf16.  MODE 1: V transpose -> [d][s].
// MODE 2: fp32 flat.
template <int MODE>
__global__ __launch_bounds__(256) void gemm_bf16(
    const __bf16* __restrict__ A, const __bf16* __restrict__ Bt,
    const float2* __restrict__ tbl, void* __restrict__ Cout) {
  __shared__ __align__(16) char smem[34816];
  short* As = (short*)smem;            // [128][32]
  short* Bs = (short*)(smem + 8192);   // [128][32]

  const int tid = threadIdx.x;
  const int lane = tid & 63, w = tid >> 6;
  const int qi = lane & 15, c = lane >> 4;
  const int wr = w >> 1, wc = w & 1;
  const int m0 = blockIdx.y * 128, n0 = blockIdx.x * 128;

  const int srow = lane >> 2;        // 0..15
  const int scol = (lane & 3) * 8;   // k elements
  const __bf16* gA = A + (size_t)(m0 + w * 16 + srow) * Dm + scol;
  const __bf16* gB = Bt + (size_t)(n0 + w * 16 + srow) * Dm + scol;
  short* lA = As + w * 512;  // wave-uniform LDS dest (bytes w*1024)
  short* lB = Bs + w * 512;

  f32x4 acc[4][4];
#pragma unroll
  for (int i = 0; i < 4; ++i)
#pragma unroll
    for (int j = 0; j < 4; ++j) acc[i][j] = (f32x4){0.f, 0.f, 0.f, 0.f};

  for (int k0 = 0; k0 < Dm; k0 += 32) {
    if (k0) __syncthreads();
    gload16(gA + k0, lA);
    gload16(gA + (size_t)64 * Dm + k0, lA + 2048);
    gload16(gB + k0, lB);
    gload16(gB + (size_t)64 * Dm + k0, lB + 2048);
    __syncthreads();
    bf16x8 af[4], bfv[4];
#pragma unroll
    for (int i = 0; i < 4; ++i) {
      af[i]  = *(bf16x8*)(As + (wr * 64 + i * 16 + qi) * 32 + c * 8);
      bfv[i] = *(bf16x8*)(Bs + (wc * 64 + i * 16 + qi) * 32 + c * 8);
    }
#pragma unroll
    for (int i = 0; i < 4; ++i)
#pragma unroll
      for (int j = 0; j < 4; ++j) acc[i][j] = mfma16(af[i], bfv[j], acc[i][j]);
  }

  if (MODE == 2) {
    float* C = (float*)Cout;
#pragma unroll
    for (int i = 0; i < 4; ++i)
#pragma unroll
      for (int j = 0; j < 4; ++j) {
        int n = n0 + wc * 64 + j * 16 + qi;
#pragma unroll
        for (int r = 0; r < 4; ++r) {
          int m = m0 + wr * 64 + i * 16 + c * 4 + r;
          C[(size_t)m * Dm + n] = acc[i][j][r];
        }
      }
  } else if (MODE == 0) {
    short* C = (short*)Cout;
#pragma unroll
    for (int j = 0; j < 4; ++j) {
      int n = n0 + wc * 64 + j * 16 + qi;
      int d = n & (DK - 1), h = n >> 6, jj = d >> 1;
#pragma unroll
      for (int i = 0; i < 4; ++i)
#pragma unroll
        for (int r = 0; r < 4; ++r) {
          int m = m0 + wr * 64 + i * 16 + c * 4 + r;
          int s = m & (Sq - 1), b = m >> 11;
          float v = acc[i][j][r];
          float p = __shfl_xor(v, 1);
          float2 t = tbl[s * 32 + jj];
          float o = (qi & 1) ? v * t.x + p * t.y : v * t.x - p * t.y;
          C[((size_t)(b * Hh + h) * Sq + s) * DK + d] = f2bf(o);
        }
    }
  } else {  // MODE 1: Vt[bh][d][s]
    __syncthreads();
    short* T = (short*)smem;  // [128][136] padded
#pragma unroll
    for (int i = 0; i < 4; ++i)
#pragma unroll
      for (int j = 0; j < 4; ++j) {
        int nl = wc * 64 + j * 16 + qi;
        int mb = wr * 64 + i * 16 + c * 4;
        short4v pk = {f2bf(acc[i][j][0]), f2bf(acc[i][j][1]),
                      f2bf(acc[i][j][2]), f2bf(acc[i][j][3])};
        *(short4v*)(T + nl * 136 + mb) = pk;
      }
    __syncthreads();
    short* C = (short*)Cout;
    int b = m0 >> 11, sb = m0 & (Sq - 1);
#pragma unroll
    for (int it = 0; it < 8; ++it) {
      int f = tid + it * 256;
      int nl = f >> 4, mc = f & 15;
      short8v v = *(short8v*)(T + nl * 136 + mc * 8);
      int ng = n0 + nl;
      int d = ng & (DK - 1), h = (ng >> 6) & (Hh - 1);
      *(short8v*)(C + ((size_t)(b * Hh + h) * DK + d) * Sq + sb + mc * 8) = v;
    }
  }
}

// ======================= Flash attention (bf16 MFMA) ========================
__global__ __launch_bounds__(256) void attn_kernel(
    const __bf16* __restrict__ Qb, const __bf16* __restrict__ Kb,
    const __bf16* __restrict__ Vt, __bf16* __restrict__ AOb) {
  __shared__ __align__(16) char Plds[4][2048];

  const int bid = blockIdx.x;
  const int qc = 31 - (bid & 31);  // big q first
  const int bh = bid >> 5;
  const int b = bh >> 4, h = bh & (Hh - 1);
  const int tid = threadIdx.x, lane = tid & 63, wave = tid >> 6;
  const int g = lane >> 4, qi = lane & 15;
  const int q0w = qc * 64 + wave * 16;

  const __bf16* Qp = Qb + (size_t)bh * Sq * DK;
  const __bf16* Kp = Kb + (size_t)bh * Sq * DK;
  const __bf16* Vp = Vt + (size_t)bh * DK * Sq;

  const bf16x8 qf0 = *(const bf16x8*)(Qp + (q0w + qi) * DK + 8 * g);
  const bf16x8 qf1 = *(const bf16x8*)(Qp + (q0w + qi) * DK + 32 + 8 * g);

  f32x4 acc[4];
#pragma unroll
  for (int j = 0; j < 4; ++j) acc[j] = (f32x4){0.f, 0.f, 0.f, 0.f};
  float m_ = -1e30f, l_ = 0.f;

  char* myP = (char*)Plds[wave];
  const int swz = (qi & 7) << 4;
  const int nt = qc + 1;

  for (int kt = 0; kt < nt; ++kt) {
    const int kbase = kt * 64;

    bf16x8 kf[4][2];
#pragma unroll
    for (int bb = 0; bb < 4; ++bb) {
      const __bf16* kr = Kp + (kbase + 16 * bb + qi) * DK + 8 * g;
      kf[bb][0] = *(const bf16x8*)kr;
      kf[bb][1] = *(const bf16x8*)(kr + 32);
    }
    bf16x8 vf[4][2];
#pragma unroll
    for (int j = 0; j < 4; ++j) {
      const __bf16* vr = Vp + (16 * j + qi) * Sq + kbase + 8 * g;
      vf[j][0] = *(const bf16x8*)vr;
      vf[j][1] = *(const bf16x8*)(vr + 32);
    }

    f32x4 st[4];
#pragma unroll
    for (int bb = 0; bb < 4; ++bb) {
      st[bb] = mfma16(kf[bb][0], qf0, (f32x4){0.f, 0.f, 0.f, 0.f});
      st[bb] = mfma16(kf[bb][1], qf1, st[bb]);
    }

    float sv[4][4];
    float tmax = -1e30f;
    const bool maskt = (kt == qc);
#pragma unroll
    for (int bb = 0; bb < 4; ++bb)
#pragma unroll
      for (int r = 0; r < 4; ++r) {
        float v = st[bb][r] * 0.125f;
        if (maskt && (kbase + 16 * bb + 4 * g + r > q0w + qi)) v = -1e30f;
        sv[bb][r] = v;
        tmax = fmaxf(tmax, v);
      }
    tmax = fmaxf(tmax, __shfl_xor(tmax, 16));
    tmax = fmaxf(tmax, __shfl_xor(tmax, 32));
    const float mnew = fmaxf(m_, tmax);
    const float corr = __expf(m_ - mnew);
    float ls = 0.f;
    unsigned int pw[4][2];
#pragma unroll
    for (int bb = 0; bb < 4; ++bb) {
      float p0 = __expf(sv[bb][0] - mnew), p1 = __expf(sv[bb][1] - mnew);
      float p2 = __expf(sv[bb][2] - mnew), p3 = __expf(sv[bb][3] - mnew);
      ls += (p0 + p1) + (p2 + p3);
      pw[bb][0] = (unsigned int)(unsigned short)f2bf(p0) |
                  ((unsigned int)(unsigned short)f2bf(p1) << 16);
      pw[bb][1] = (unsigned int)(unsigned short)f2bf(p2) |
                  ((unsigned int)(unsigned short)f2bf(p3) << 16);
    }
    ls += __shfl_xor(ls, 16);
    ls += __shfl_xor(ls, 32);
    l_ = l_ * corr + ls;
    m_ = mnew;

#pragma unroll
    for (int bb = 0; bb < 4; ++bb)
      *(uint2*)(myP + qi * 128 + ((32 * bb + 8 * g) ^ swz)) =
          make_uint2(pw[bb][0], pw[bb][1]);

    float cr[4];
#pragma unroll
    for (int r = 0; r < 4; ++r) cr[r] = __shfl(corr, 4 * g + r);
#pragma unroll
    for (int j = 0; j < 4; ++j) {
      acc[j][0] *= cr[0]; acc[j][1] *= cr[1];
      acc[j][2] *= cr[2]; acc[j][3] *= cr[3];
    }

    bf16x8 pa0 = *(bf16x8*)(myP + qi * 128 + ((16 * g) ^ swz));
    bf16x8 pa1 = *(bf16x8*)(myP + qi * 128 + ((64 + 16 * g) ^ swz));
#pragma unroll
    for (int j = 0; j < 4; ++j) {
      acc[j] = mfma16(pa0, vf[j][0], acc[j]);
      acc[j] = mfma16(pa1, vf[j][1], acc[j]);
    }
  }

  const float inv = 1.f / l_;
  float ir[4];
#pragma unroll
  for (int r = 0; r < 4; ++r) ir[r] = __shfl(inv, 4 * g + r);
  short* AOs = (short*)AOb;
#pragma unroll
  for (int j = 0; j < 4; ++j)
#pragma unroll
    for (int r = 0; r < 4; ++r)
      AOs[((size_t)b * Sq + q0w + 4 * g + r) * Dm + h * DK + 16 * j + qi] =
          f2bf(acc[j][r] * ir[r]);
}

// ================================ launch ===================================
extern "C" void kernel_launch(void* const* d_in, const int* in_sizes, int n_in,
                              void* d_out, int out_size, void* d_ws,
                              size_t ws_size, hipStream_t stream) {
  const float* x  = (const float*)d_in[0];
  const float* Wq = (const float*)d_in[1];
  const float* Wk = (const float*)d_in[2];
  const float* Wv = (const float*)d_in[3];
  const float* Wo = (const float*)d_in[4];
  float* out = (float*)d_out;

  char* w = (char*)d_ws;
  __bf16* Qb  = (__bf16*)(w);                 // 8 MB [bh][s][64]
  __bf16* Kb  = (__bf16*)(w + (8u << 20));    // 8 MB
  __bf16* Vt  = (__bf16*)(w + (16u << 20));   // 8 MB [bh][64][s]
  __bf16* AOb = (__bf16*)(w + (24u << 20));   // 8 MB [B,S,D]
  __bf16* xb  = (__bf16*)(w + (32u << 20));   // 8 MB [4096][1024]
  __bf16* Wt  = (__bf16*)(w + (40u << 20));   // 4 x 2 MB [n][k]
  float2* tbl = (float2*)(w + (48u << 20));   // 512 KB

  const size_t WSZ = (size_t)Dm * Dm;
  conv_x_kernel<<<2048, 256, 0, stream>>>(x, xb);
  conv_wt_kernel<<<dim3(32, 32, 4), 256, 0, stream>>>(Wq, Wk, Wv, Wo, Wt);
  rope_tbl_kernel<<<256, 256, 0, stream>>>(tbl);

  dim3 gg(Dm / 128, Mrows / 128);
  gemm_bf16<0><<<gg, 256, 0, stream>>>(xb, Wt + 0 * WSZ, tbl, (void*)Qb);
  gemm_bf16<0><<<gg, 256, 0, stream>>>(xb, Wt + 1 * WSZ, tbl, (void*)Kb);
  gemm_bf16<1><<<gg, 256, 0, stream>>>(xb, Wt + 2 * WSZ, nullptr, (void*)Vt);
  attn_kernel<<<Bz * Hh * (Sq / 64), 256, 0, stream>>>(Qb, Kb, Vt, AOb);
  gemm_bf16<2><<<gg, 256, 0, stream>>>(AOb, Wt + 3 * WSZ, nullptr, (void*)out);
}

// Round 4
// 300.230 us; speedup vs baseline: 5.9384x; 1.1582x over previous
//
#include <hip/hip_runtime.h>
#include <cmath>

// ---------------------------------------------------------------------------
// MHA forward, bf16-MFMA everywhere.
//   prep:  x->bf16 ; Wq/Wk/Wv/Wo -> bf16 transposed [n][k] ; RoPE table
//   gemm<0>: xb@Wt -> RoPE -> Qb/Kb bf16 [bh][s][64]
//   gemm<1>: xb@Wt -> Vt bf16 [bh][64][s]  (LDS-transposed epilogue)
//   attn:    causal flash attention (mfma 16x16x32 bf16), XCD-partitioned,
//            K-prefetch double-buffer -> AOb bf16 [B,S,D]
//   gemm<2>: AOb@Wto -> out fp32
// B=2 S=2048 D=1024 H=16 dk=64
// ---------------------------------------------------------------------------

constexpr int Bz = 2, Sq = 2048, Dm = 1024, Hh = 16, DK = 64;
constexpr int Mrows = Bz * Sq;  // 4096

typedef __attribute__((ext_vector_type(4))) float f32x4;
typedef __attribute__((ext_vector_type(8))) __bf16 bf16x8;
typedef __attribute__((ext_vector_type(4))) short short4v;
typedef __attribute__((ext_vector_type(8))) short short8v;

__device__ __forceinline__ f32x4 mfma16(bf16x8 a, bf16x8 b, f32x4 c) {
  return __builtin_amdgcn_mfma_f32_16x16x32_bf16(a, b, c, 0, 0, 0);
}
__device__ __forceinline__ short f2bf(float x) {
  union { float f; unsigned u; } v;
  v.f = x;
  unsigned r = v.u + 0x7fff + ((v.u >> 16) & 1);  // RNE
  return (short)(r >> 16);
}
// async global->LDS, 16 B per lane; lds ptr must be wave-uniform
__device__ __forceinline__ void gload16(const void* g, void* l) {
  __builtin_amdgcn_global_load_lds(
      (__attribute__((address_space(1))) void*)g,
      (__attribute__((address_space(3))) void*)l, 16, 0, 0);
}

// ============================ prep kernels =================================
__global__ __launch_bounds__(256) void conv_x_kernel(
    const float* __restrict__ in, __bf16* __restrict__ outb) {
  int t = blockIdx.x * 256 + threadIdx.x;  // 524288 threads, 8 elems each
  const float4* p = (const float4*)in + (size_t)t * 2;
  float4 a = p[0], b = p[1];
  short8v o = {f2bf(a.x), f2bf(a.y), f2bf(a.z), f2bf(a.w),
               f2bf(b.x), f2bf(b.y), f2bf(b.z), f2bf(b.w)};
  *(short8v*)((short*)outb + (size_t)t * 8) = o;
}

// W[k][n] fp32 -> Wt[n][k] bf16, 4 tensors
__global__ __launch_bounds__(256) void conv_wt_kernel(
    const float* __restrict__ Wq, const float* __restrict__ Wk,
    const float* __restrict__ Wv, const float* __restrict__ Wo,
    __bf16* __restrict__ outb) {
  __shared__ float tile[32][33];
  int z = blockIdx.z;
  const float* W = (z == 0) ? Wq : (z == 1) ? Wk : (z == 2) ? Wv : Wo;
  short* out = (short*)outb + (size_t)z * Dm * Dm;
  int r0 = blockIdx.y * 32, c0 = blockIdx.x * 32;
  int t = threadIdx.x;
  int r = t >> 3, c4 = (t & 7) * 4;
  float4 v = *(const float4*)&W[(size_t)(r0 + r) * Dm + c0 + c4];
  tile[r][c4] = v.x; tile[r][c4 + 1] = v.y;
  tile[r][c4 + 2] = v.z; tile[r][c4 + 3] = v.w;
  __syncthreads();
  int nl = t >> 3, k4 = (t & 7) * 4;
  short4v o = {f2bf(tile[k4][nl]), f2bf(tile[k4 + 1][nl]),
               f2bf(tile[k4 + 2][nl]), f2bf(tile[k4 + 3][nl])};
  *(short4v*)&out[(size_t)(c0 + nl) * Dm + r0 + k4] = o;
}

// tbl[s][j] = (cos, sin)(s * 10000^(-j/32)), s<2048, j<32
__global__ __launch_bounds__(256) void rope_tbl_kernel(float2* __restrict__ tbl) {
  int t = blockIdx.x * 256 + threadIdx.x;  // 65536
  int s = t >> 5, j = t & 31;
  float inv = exp2f(-13.287712379549449f * (1.0f / 32.0f) * (float)j);
  float sn, cs;
  sincosf((float)s * inv, &sn, &cs);
  tbl[t] = make_float2(cs, sn);
}

// ========================= bf16 MFMA GEMM ==================================
// C[4096][1024] = A[4096][1024] @ Bt[n][k]^T. 128x128 tile, BK=32, 4 waves.
// MODE 0: RoPE epilogue -> head-layout bf16.  MODE 1: V transpose -> [d][s].
// MODE 2: fp32 flat.
template <int MODE>
__global__ __launch_bounds__(256) void gemm_bf16(
    const __bf16* __restrict__ A, const __bf16* __restrict__ Bt,
    const float2* __restrict__ tbl, void* __restrict__ Cout) {
  __shared__ __align__(16) char smem[34816];
  short* As = (short*)smem;            // [128][32]
  short* Bs = (short*)(smem + 8192);   // [128][32]

  const int tid = threadIdx.x;
  const int lane = tid & 63, w = tid >> 6;
  const int qi = lane & 15, c = lane >> 4;
  const int wr = w >> 1, wc = w & 1;
  const int m0 = blockIdx.y * 128, n0 = blockIdx.x * 128;

  const int srow = lane >> 2;        // 0..15
  const int scol = (lane & 3) * 8;   // k elements
  const __bf16* gA = A + (size_t)(m0 + w * 16 + srow) * Dm + scol;
  const __bf16* gB = Bt + (size_t)(n0 + w * 16 + srow) * Dm + scol;
  short* lA = As + w * 512;  // wave-uniform LDS dest (bytes w*1024)
  short* lB = Bs + w * 512;

  f32x4 acc[4][4];
#pragma unroll
  for (int i = 0; i < 4; ++i)
#pragma unroll
    for (int j = 0; j < 4; ++j) acc[i][j] = (f32x4){0.f, 0.f, 0.f, 0.f};

  for (int k0 = 0; k0 < Dm; k0 += 32) {
    if (k0) __syncthreads();
    gload16(gA + k0, lA);
    gload16(gA + (size_t)64 * Dm + k0, lA + 2048);
    gload16(gB + k0, lB);
    gload16(gB + (size_t)64 * Dm + k0, lB + 2048);
    __syncthreads();
    bf16x8 af[4], bfv[4];
#pragma unroll
    for (int i = 0; i < 4; ++i) {
      af[i]  = *(bf16x8*)(As + (wr * 64 + i * 16 + qi) * 32 + c * 8);
      bfv[i] = *(bf16x8*)(Bs + (wc * 64 + i * 16 + qi) * 32 + c * 8);
    }
#pragma unroll
    for (int i = 0; i < 4; ++i)
#pragma unroll
      for (int j = 0; j < 4; ++j) acc[i][j] = mfma16(af[i], bfv[j], acc[i][j]);
  }

  if (MODE == 2) {
    float* C = (float*)Cout;
#pragma unroll
    for (int i = 0; i < 4; ++i)
#pragma unroll
      for (int j = 0; j < 4; ++j) {
        int n = n0 + wc * 64 + j * 16 + qi;
#pragma unroll
        for (int r = 0; r < 4; ++r) {
          int m = m0 + wr * 64 + i * 16 + c * 4 + r;
          C[(size_t)m * Dm + n] = acc[i][j][r];
        }
      }
  } else if (MODE == 0) {
    short* C = (short*)Cout;
#pragma unroll
    for (int j = 0; j < 4; ++j) {
      int n = n0 + wc * 64 + j * 16 + qi;
      int d = n & (DK - 1), h = n >> 6, jj = d >> 1;
#pragma unroll
      for (int i = 0; i < 4; ++i)
#pragma unroll
        for (int r = 0; r < 4; ++r) {
          int m = m0 + wr * 64 + i * 16 + c * 4 + r;
          int s = m & (Sq - 1), b = m >> 11;
          float v = acc[i][j][r];
          float p = __shfl_xor(v, 1);
          float2 t = tbl[s * 32 + jj];
          float o = (qi & 1) ? v * t.x + p * t.y : v * t.x - p * t.y;
          C[((size_t)(b * Hh + h) * Sq + s) * DK + d] = f2bf(o);
        }
    }
  } else {  // MODE 1: Vt[bh][d][s]
    __syncthreads();
    short* T = (short*)smem;  // [128][136] padded
#pragma unroll
    for (int i = 0; i < 4; ++i)
#pragma unroll
      for (int j = 0; j < 4; ++j) {
        int nl = wc * 64 + j * 16 + qi;
        int mb = wr * 64 + i * 16 + c * 4;
        short4v pk = {f2bf(acc[i][j][0]), f2bf(acc[i][j][1]),
                      f2bf(acc[i][j][2]), f2bf(acc[i][j][3])};
        *(short4v*)(T + nl * 136 + mb) = pk;
      }
    __syncthreads();
    short* C = (short*)Cout;
    int b = m0 >> 11, sb = m0 & (Sq - 1);
#pragma unroll
    for (int it = 0; it < 8; ++it) {
      int f = tid + it * 256;
      int nl = f >> 4, mc = f & 15;
      short8v v = *(short8v*)(T + nl * 136 + mc * 8);
      int ng = n0 + nl;
      int d = ng & (DK - 1), h = (ng >> 6) & (Hh - 1);
      *(short8v*)(C + ((size_t)(b * Hh + h) * DK + d) * Sq + sb + mc * 8) = v;
    }
  }
}

// ======================= Flash attention (bf16 MFMA) ========================
// 256 thr = 4 waves; wave -> 16 q-rows; block -> (bh, 64-row q-chunk).
// XCD-partitioned: xcd = bid&7 owns heads 4*xcd..4*xcd+3 (K/V fit its L2).
// K double-buffer register prefetch; V issued at tile top, used post-softmax.
__global__ __launch_bounds__(256) void attn_kernel(
    const __bf16* __restrict__ Qb, const __bf16* __restrict__ Kb,
    const __bf16* __restrict__ Vt, __bf16* __restrict__ AOb) {
  __shared__ __align__(16) char Plds[4][2048];

  const int bid = blockIdx.x;            // 1024
  const int xcd = bid & 7;               // hw round-robin -> XCD id (heuristic)
  const int idx = bid >> 3;              // 0..127 within XCD
  const int bh = (xcd << 2) | (idx >> 5);
  const int qc = 31 - (idx & 31);        // big q first within XCD
  const int b = bh >> 4, h = bh & (Hh - 1);
  const int tid = threadIdx.x, lane = tid & 63, wave = tid >> 6;
  const int g = lane >> 4, qi = lane & 15;
  const int q0w = qc * 64 + wave * 16;

  const __bf16* Qp = Qb + (size_t)bh * Sq * DK;
  const __bf16* Kp = Kb + (size_t)bh * Sq * DK;
  const __bf16* Vp = Vt + (size_t)bh * DK * Sq;

  const bf16x8 qf0 = *(const bf16x8*)(Qp + (q0w + qi) * DK + 8 * g);
  const bf16x8 qf1 = *(const bf16x8*)(Qp + (q0w + qi) * DK + 32 + 8 * g);

  f32x4 acc[4];
#pragma unroll
  for (int j = 0; j < 4; ++j) acc[j] = (f32x4){0.f, 0.f, 0.f, 0.f};
  float m_ = -1e30f, l_ = 0.f;

  char* myP = (char*)Plds[wave];
  const int swz = (qi & 7) << 4;
  const int nt = qc + 1;
  // scale folded into base-2 domain: S' = S * 0.125 * log2(e)
  const float SC = 0.125f * 1.44269504f;

  bf16x8 kA[4][2], kB[4][2], vf[4][2];

  auto loadK = [&](bf16x8 (&kf)[4][2], int kt) {
    const int kbase = kt * 64;
#pragma unroll
    for (int bb = 0; bb < 4; ++bb) {
      const __bf16* kr = Kp + (kbase + 16 * bb + qi) * DK + 8 * g;
      kf[bb][0] = *(const bf16x8*)kr;
      kf[bb][1] = *(const bf16x8*)(kr + 32);
    }
  };
  auto loadV = [&](int kt) {
    const int kbase = kt * 64;
#pragma unroll
    for (int j = 0; j < 4; ++j) {
      const __bf16* vr = Vp + (16 * j + qi) * Sq + kbase + 8 * g;
      vf[j][0] = *(const bf16x8*)vr;
      vf[j][1] = *(const bf16x8*)(vr + 32);
    }
  };
  auto tile = [&](const bf16x8 (&kf)[4][2], int kt) {
    const int kbase = kt * 64;
    f32x4 st[4];
#pragma unroll
    for (int bb = 0; bb < 4; ++bb) {
      st[bb] = mfma16(kf[bb][0], qf0, (f32x4){0.f, 0.f, 0.f, 0.f});
      st[bb] = mfma16(kf[bb][1], qf1, st[bb]);
    }

    float sv[4][4];
    float tmax = -1e30f;
    const bool maskt = (kt == qc);
#pragma unroll
    for (int bb = 0; bb < 4; ++bb)
#pragma unroll
      for (int r = 0; r < 4; ++r) {
        float v = st[bb][r] * SC;
        if (maskt && (kbase + 16 * bb + 4 * g + r > q0w + qi)) v = -1e30f;
        sv[bb][r] = v;
        tmax = fmaxf(tmax, v);
      }
    tmax = fmaxf(tmax, __shfl_xor(tmax, 16));
    tmax = fmaxf(tmax, __shfl_xor(tmax, 32));
    const float mnew = fmaxf(m_, tmax);
    const float corr = exp2f(m_ - mnew);
    float ls = 0.f;
    unsigned int pw[4][2];
#pragma unroll
    for (int bb = 0; bb < 4; ++bb) {
      float p0 = exp2f(sv[bb][0] - mnew), p1 = exp2f(sv[bb][1] - mnew);
      float p2 = exp2f(sv[bb][2] - mnew), p3 = exp2f(sv[bb][3] - mnew);
      ls += (p0 + p1) + (p2 + p3);
      pw[bb][0] = (unsigned int)(unsigned short)f2bf(p0) |
                  ((unsigned int)(unsigned short)f2bf(p1) << 16);
      pw[bb][1] = (unsigned int)(unsigned short)f2bf(p2) |
                  ((unsigned int)(unsigned short)f2bf(p3) << 16);
    }
    ls += __shfl_xor(ls, 16);
    ls += __shfl_xor(ls, 32);
    l_ = l_ * corr + ls;
    m_ = mnew;

#pragma unroll
    for (int bb = 0; bb < 4; ++bb)
      *(uint2*)(myP + qi * 128 + ((32 * bb + 8 * g) ^ swz)) =
          make_uint2(pw[bb][0], pw[bb][1]);

    float cr[4];
#pragma unroll
    for (int r = 0; r < 4; ++r) cr[r] = __shfl(corr, 4 * g + r);
#pragma unroll
    for (int j = 0; j < 4; ++j) {
      acc[j][0] *= cr[0]; acc[j][1] *= cr[1];
      acc[j][2] *= cr[2]; acc[j][3] *= cr[3];
    }

    bf16x8 pa0 = *(bf16x8*)(myP + qi * 128 + ((16 * g) ^ swz));
    bf16x8 pa1 = *(bf16x8*)(myP + qi * 128 + ((64 + 16 * g) ^ swz));
#pragma unroll
    for (int j = 0; j < 4; ++j) {
      acc[j] = mfma16(pa0, vf[j][0], acc[j]);
      acc[j] = mfma16(pa1, vf[j][1], acc[j]);
    }
  };

  loadK(kA, 0);
  int kt = 0;
  for (;;) {
    loadV(kt);
    if (kt + 1 < nt) loadK(kB, kt + 1);
    tile(kA, kt);
    if (++kt >= nt) break;
    loadV(kt);
    if (kt + 1 < nt) loadK(kA, kt + 1);
    tile(kB, kt);
    if (++kt >= nt) break;
  }

  const float inv = 1.f / l_;
  float ir[4];
#pragma unroll
  for (int r = 0; r < 4; ++r) ir[r] = __shfl(inv, 4 * g + r);
  short* AOs = (short*)AOb;
#pragma unroll
  for (int j = 0; j < 4; ++j)
#pragma unroll
    for (int r = 0; r < 4; ++r)
      AOs[((size_t)b * Sq + q0w + 4 * g + r) * Dm + h * DK + 16 * j + qi] =
          f2bf(acc[j][r] * ir[r]);
}

// ================================ launch ===================================
extern "C" void kernel_launch(void* const* d_in, const int* in_sizes, int n_in,
                              void* d_out, int out_size, void* d_ws,
                              size_t ws_size, hipStream_t stream) {
  const float* x  = (const float*)d_in[0];
  const float* Wq = (const float*)d_in[1];
  const float* Wk = (const float*)d_in[2];
  const float* Wv = (const float*)d_in[3];
  const float* Wo = (const float*)d_in[4];
  float* out = (float*)d_out;

  char* w = (char*)d_ws;
  __bf16* Qb  = (__bf16*)(w);                 // 8 MB [bh][s][64]
  __bf16* Kb  = (__bf16*)(w + (8u << 20));    // 8 MB
  __bf16* Vt  = (__bf16*)(w + (16u << 20));   // 8 MB [bh][64][s]
  __bf16* AOb = (__bf16*)(w + (24u << 20));   // 8 MB [B,S,D]
  __bf16* xb  = (__bf16*)(w + (32u << 20));   // 8 MB [4096][1024]
  __bf16* Wt  = (__bf16*)(w + (40u << 20));   // 4 x 2 MB [n][k]
  float2* tbl = (float2*)(w + (48u << 20));   // 512 KB

  const size_t WSZ = (size_t)Dm * Dm;
  conv_x_kernel<<<2048, 256, 0, stream>>>(x, xb);
  conv_wt_kernel<<<dim3(32, 32, 4), 256, 0, stream>>>(Wq, Wk, Wv, Wo, Wt);
  rope_tbl_kernel<<<256, 256, 0, stream>>>(tbl);

  dim3 gg(Dm / 128, Mrows / 128);
  gemm_bf16<0><<<gg, 256, 0, stream>>>(xb, Wt + 0 * WSZ, tbl, (void*)Qb);
  gemm_bf16<0><<<gg, 256, 0, stream>>>(xb, Wt + 1 * WSZ, tbl, (void*)Kb);
  gemm_bf16<1><<<gg, 256, 0, stream>>>(xb, Wt + 2 * WSZ, nullptr, (void*)Vt);
  attn_kernel<<<Bz * Hh * (Sq / 64), 256, 0, stream>>>(Qb, Kb, Vt, AOb);
  gemm_bf16<2><<<gg, 256, 0, stream>>>(AOb, Wt + 3 * WSZ, nullptr, (void*)out);
}

// Round 6
// 178.684 us; speedup vs baseline: 9.9779x; 1.6802x over previous
//
#include <hip/hip_runtime.h>
#include <cmath>

// ---------------------------------------------------------------------------
// MHA forward, bf16-MFMA everywhere.
//   prep:  x->bf16 ; Wq/Wk/Wv/Wo -> bf16 transposed [n][k] ; RoPE table
//   gemm<0>: xb@Wt -> RoPE -> Qb/Kb bf16 [bh][s][64]
//   gemm<1>: xb@Wt -> Vt bf16 [bh][64][s]  (LDS-transposed epilogue)
//   attn:    causal flash attention (mfma 16x16x32 bf16), XCD-partitioned,
//            paired q-chunks (uniform 33 tiles/block), K/V LDS double-buffer
//            via swizzled-source global_load_lds -> AOb bf16 [B,S,D]
//   gemm<2>: AOb@Wto -> out fp32
// B=2 S=2048 D=1024 H=16 dk=64
// ---------------------------------------------------------------------------

constexpr int Bz = 2, Sq = 2048, Dm = 1024, Hh = 16, DK = 64;
constexpr int Mrows = Bz * Sq;  // 4096

typedef __attribute__((ext_vector_type(4))) float f32x4;
typedef __attribute__((ext_vector_type(8))) __bf16 bf16x8;
typedef __attribute__((ext_vector_type(4))) short short4v;
typedef __attribute__((ext_vector_type(8))) short short8v;

__device__ __forceinline__ f32x4 mfma16(bf16x8 a, bf16x8 b, f32x4 c) {
  return __builtin_amdgcn_mfma_f32_16x16x32_bf16(a, b, c, 0, 0, 0);
}
__device__ __forceinline__ short f2bf(float x) {
  union { float f; unsigned u; } v;
  v.f = x;
  unsigned r = v.u + 0x7fff + ((v.u >> 16) & 1);  // RNE
  return (short)(r >> 16);
}
// async global->LDS, 16 B per lane; lds ptr must be wave-uniform
__device__ __forceinline__ void gload16(const void* g, void* l) {
  __builtin_amdgcn_global_load_lds(
      (__attribute__((address_space(1))) void*)g,
      (__attribute__((address_space(3))) void*)l, 16, 0, 0);
}

// ============================ prep kernels =================================
__global__ __launch_bounds__(256) void conv_x_kernel(
    const float* __restrict__ in, __bf16* __restrict__ outb) {
  int t = blockIdx.x * 256 + threadIdx.x;  // 524288 threads, 8 elems each
  const float4* p = (const float4*)in + (size_t)t * 2;
  float4 a = p[0], b = p[1];
  short8v o = {f2bf(a.x), f2bf(a.y), f2bf(a.z), f2bf(a.w),
               f2bf(b.x), f2bf(b.y), f2bf(b.z), f2bf(b.w)};
  *(short8v*)((short*)outb + (size_t)t * 8) = o;
}

// W[k][n] fp32 -> Wt[n][k] bf16, 4 tensors
__global__ __launch_bounds__(256) void conv_wt_kernel(
    const float* __restrict__ Wq, const float* __restrict__ Wk,
    const float* __restrict__ Wv, const float* __restrict__ Wo,
    __bf16* __restrict__ outb) {
  __shared__ float tile[32][33];
  int z = blockIdx.z;
  const float* W = (z == 0) ? Wq : (z == 1) ? Wk : (z == 2) ? Wv : Wo;
  short* out = (short*)outb + (size_t)z * Dm * Dm;
  int r0 = blockIdx.y * 32, c0 = blockIdx.x * 32;
  int t = threadIdx.x;
  int r = t >> 3, c4 = (t & 7) * 4;
  float4 v = *(const float4*)&W[(size_t)(r0 + r) * Dm + c0 + c4];
  tile[r][c4] = v.x; tile[r][c4 + 1] = v.y;
  tile[r][c4 + 2] = v.z; tile[r][c4 + 3] = v.w;
  __syncthreads();
  int nl = t >> 3, k4 = (t & 7) * 4;
  short4v o = {f2bf(tile[k4][nl]), f2bf(tile[k4 + 1][nl]),
               f2bf(tile[k4 + 2][nl]), f2bf(tile[k4 + 3][nl])};
  *(short4v*)&out[(size_t)(c0 + nl) * Dm + r0 + k4] = o;
}

// tbl[s][j] = (cos, sin)(s * 10000^(-j/32)), s<2048, j<32
__global__ __launch_bounds__(256) void rope_tbl_kernel(float2* __restrict__ tbl) {
  int t = blockIdx.x * 256 + threadIdx.x;  // 65536
  int s = t >> 5, j = t & 31;
  float inv = exp2f(-13.287712379549449f * (1.0f / 32.0f) * (float)j);
  float sn, cs;
  sincosf((float)s * inv, &sn, &cs);
  tbl[t] = make_float2(cs, sn);
}

// ========================= bf16 MFMA GEMM ==================================
// C[4096][1024] = A[4096][1024] @ Bt[n][k]^T. 128x128 tile, BK=32, 4 waves.
template <int MODE>
__global__ __launch_bounds__(256) void gemm_bf16(
    const __bf16* __restrict__ A, const __bf16* __restrict__ Bt,
    const float2* __restrict__ tbl, void* __restrict__ Cout) {
  __shared__ __align__(16) char smem[34816];
  short* As = (short*)smem;            // [128][32]
  short* Bs = (short*)(smem + 8192);   // [128][32]

  const int tid = threadIdx.x;
  const int lane = tid & 63, w = tid >> 6;
  const int qi = lane & 15, c = lane >> 4;
  const int wr = w >> 1, wc = w & 1;
  const int m0 = blockIdx.y * 128, n0 = blockIdx.x * 128;

  const int srow = lane >> 2;        // 0..15
  const int scol = (lane & 3) * 8;   // k elements
  const __bf16* gA = A + (size_t)(m0 + w * 16 + srow) * Dm + scol;
  const __bf16* gB = Bt + (size_t)(n0 + w * 16 + srow) * Dm + scol;
  short* lA = As + w * 512;  // wave-uniform LDS dest (bytes w*1024)
  short* lB = Bs + w * 512;

  f32x4 acc[4][4];
#pragma unroll
  for (int i = 0; i < 4; ++i)
#pragma unroll
    for (int j = 0; j < 4; ++j) acc[i][j] = (f32x4){0.f, 0.f, 0.f, 0.f};

  for (int k0 = 0; k0 < Dm; k0 += 32) {
    if (k0) __syncthreads();
    gload16(gA + k0, lA);
    gload16(gA + (size_t)64 * Dm + k0, lA + 2048);
    gload16(gB + k0, lB);
    gload16(gB + (size_t)64 * Dm + k0, lB + 2048);
    __syncthreads();
    bf16x8 af[4], bfv[4];
#pragma unroll
    for (int i = 0; i < 4; ++i) {
      af[i]  = *(bf16x8*)(As + (wr * 64 + i * 16 + qi) * 32 + c * 8);
      bfv[i] = *(bf16x8*)(Bs + (wc * 64 + i * 16 + qi) * 32 + c * 8);
    }
#pragma unroll
    for (int i = 0; i < 4; ++i)
#pragma unroll
      for (int j = 0; j < 4; ++j) acc[i][j] = mfma16(af[i], bfv[j], acc[i][j]);
  }

  if (MODE == 2) {
    float* C = (float*)Cout;
#pragma unroll
    for (int i = 0; i < 4; ++i)
#pragma unroll
      for (int j = 0; j < 4; ++j) {
        int n = n0 + wc * 64 + j * 16 + qi;
#pragma unroll
        for (int r = 0; r < 4; ++r) {
          int m = m0 + wr * 64 + i * 16 + c * 4 + r;
          C[(size_t)m * Dm + n] = acc[i][j][r];
        }
      }
  } else if (MODE == 0) {
    short* C = (short*)Cout;
#pragma unroll
    for (int j = 0; j < 4; ++j) {
      int n = n0 + wc * 64 + j * 16 + qi;
      int d = n & (DK - 1), h = n >> 6, jj = d >> 1;
#pragma unroll
      for (int i = 0; i < 4; ++i)
#pragma unroll
        for (int r = 0; r < 4; ++r) {
          int m = m0 + wr * 64 + i * 16 + c * 4 + r;
          int s = m & (Sq - 1), b = m >> 11;
          float v = acc[i][j][r];
          float p = __shfl_xor(v, 1);
          float2 t = tbl[s * 32 + jj];
          float o = (qi & 1) ? v * t.x + p * t.y : v * t.x - p * t.y;
          C[((size_t)(b * Hh + h) * Sq + s) * DK + d] = f2bf(o);
        }
    }
  } else {  // MODE 1: Vt[bh][d][s]
    __syncthreads();
    short* T = (short*)smem;  // [128][136] padded
#pragma unroll
    for (int i = 0; i < 4; ++i)
#pragma unroll
      for (int j = 0; j < 4; ++j) {
        int nl = wc * 64 + j * 16 + qi;
        int mb = wr * 64 + i * 16 + c * 4;
        short4v pk = {f2bf(acc[i][j][0]), f2bf(acc[i][j][1]),
                      f2bf(acc[i][j][2]), f2bf(acc[i][j][3])};
        *(short4v*)(T + nl * 136 + mb) = pk;
      }
    __syncthreads();
    short* C = (short*)Cout;
    int b = m0 >> 11, sb = m0 & (Sq - 1);
#pragma unroll
    for (int it = 0; it < 8; ++it) {
      int f = tid + it * 256;
      int nl = f >> 4, mc = f & 15;
      short8v v = *(short8v*)(T + nl * 136 + mc * 8);
      int ng = n0 + nl;
      int d = ng & (DK - 1), h = (ng >> 6) & (Hh - 1);
      *(short8v*)(C + ((size_t)(b * Hh + h) * DK + d) * Sq + sb + mc * 8) = v;
    }
  }
}

// ======================= Flash attention (bf16 MFMA) ========================
// 512 blocks x 4 waves. Block -> (bh, paired q-chunks qcA=pair, qcB=31-pair):
// uniform 33 k-tiles per block. XCD-partitioned (bid&7 -> 4 heads).
// K/V tiles staged in LDS (double-buffered) via global_load_lds with
// pre-swizzled per-lane SOURCE address; swizzled ds_read_b128 fragments.
__global__ __launch_bounds__(256) void attn_kernel(
    const __bf16* __restrict__ Qb, const __bf16* __restrict__ Kb,
    const __bf16* __restrict__ Vt, __bf16* __restrict__ AOb) {
  // LDS: K[2][8KB] V[2][8KB] P[4][2KB] = 40960 B
  __shared__ __align__(16) char smem[40960];

  const int bid = blockIdx.x;            // 512
  const int xcd = bid & 7;               // hw round-robin -> XCD id (heuristic)
  const int idx = bid >> 3;              // 0..63 within XCD
  const int bh = (xcd << 2) | (idx >> 4);
  const int pair = idx & 15;             // qcA = pair, qcB = 31-pair
  const int b = bh >> 4, h = bh & (Hh - 1);
  const int tid = threadIdx.x, lane = tid & 63, wave = tid >> 6;
  const int g = lane >> 4, qi = lane & 15;

  const __bf16* Qp = Qb + (size_t)bh * Sq * DK;
  const __bf16* Kp = Kb + (size_t)bh * Sq * DK;
  const __bf16* Vp = Vt + (size_t)bh * DK * Sq;

  char* myP = smem + 32768 + wave * 2048;
  const int swz = (qi & 7) << 4;
  const float SC = 0.125f * 1.44269504f;  // scale * log2(e)

  // staging geometry: 8 rows per 1KB segment; this lane's row/col within seg
  const int srow8 = lane >> 3;           // 0..7
  const int scol16 = lane & 7;           // col16 within 128B row
  short* AOs = (short*)AOb;

  // stage K+V tile kt into buffer cb: wave handles segments 2w,2w+1
  auto stage = [&](int cb, int kt) {
    const int kbase = kt * 64;
    char* Kd = smem + cb * 8192;
    char* Vd = smem + 16384 + cb * 8192;
#pragma unroll
    for (int s2 = 0; s2 < 2; ++s2) {
      int seg = wave * 2 + s2;
      int r = seg * 8 + srow8;                       // 0..63
      int csrc = ((scol16 ^ (r & 7)) << 3);          // swizzled source col
      gload16(Kp + (size_t)(kbase + r) * DK + csrc, Kd + seg * 1024);
      gload16(Vp + (size_t)r * Sq + kbase + csrc, Vd + seg * 1024);
    }
  };

  auto run_chunk = [&](int qc) {
    const int q0w = qc * 64 + wave * 16;
    const int nt = qc + 1;

    const bf16x8 qf0 = *(const bf16x8*)(Qp + (q0w + qi) * DK + 8 * g);
    const bf16x8 qf1 = *(const bf16x8*)(Qp + (q0w + qi) * DK + 32 + 8 * g);

    f32x4 acc[4];
#pragma unroll
    for (int j = 0; j < 4; ++j) acc[j] = (f32x4){0.f, 0.f, 0.f, 0.f};
    float m_ = -1e30f, l_ = 0.f;

    __syncthreads();  // protect buffers from previous chunk's readers
    stage(0, 0);

    int cur = 0;
    for (int kt = 0; kt < nt; ++kt) {
      __syncthreads();  // buf[cur] staged (drains vmcnt on all waves)
      if (kt + 1 < nt) stage(cur ^ 1, kt + 1);

      const char* Kt = smem + cur * 8192;
      const char* Vv = smem + 16384 + cur * 8192;
      const int kbase = kt * 64;

      // K fragments from swizzled LDS: row rr=16bb+qi, col16 g / g+4
      bf16x8 kf[4][2];
#pragma unroll
      for (int bb = 0; bb < 4; ++bb) {
        int rr = 16 * bb + qi;
        kf[bb][0] = *(const bf16x8*)(Kt + rr * 128 + ((g ^ (rr & 7)) << 4));
        kf[bb][1] = *(const bf16x8*)(Kt + rr * 128 + (((g + 4) ^ (rr & 7)) << 4));
      }

      f32x4 st[4];
#pragma unroll
      for (int bb = 0; bb < 4; ++bb) {
        st[bb] = mfma16(kf[bb][0], qf0, (f32x4){0.f, 0.f, 0.f, 0.f});
        st[bb] = mfma16(kf[bb][1], qf1, st[bb]);
      }

      // V fragments (independent of softmax; latency hides under it)
      bf16x8 vf[4][2];
#pragma unroll
      for (int j = 0; j < 4; ++j) {
        int rr = 16 * j + qi;
        vf[j][0] = *(const bf16x8*)(Vv + rr * 128 + ((g ^ (rr & 7)) << 4));
        vf[j][1] = *(const bf16x8*)(Vv + rr * 128 + (((g + 4) ^ (rr & 7)) << 4));
      }

      float sv[4][4];
      float tmax = -1e30f;
      const bool maskt = (kt == qc);
#pragma unroll
      for (int bb = 0; bb < 4; ++bb)
#pragma unroll
        for (int r = 0; r < 4; ++r) {
          float v = st[bb][r] * SC;
          if (maskt && (kbase + 16 * bb + 4 * g + r > q0w + qi)) v = -1e30f;
          sv[bb][r] = v;
          tmax = fmaxf(tmax, v);
        }
      tmax = fmaxf(tmax, __shfl_xor(tmax, 16));
      tmax = fmaxf(tmax, __shfl_xor(tmax, 32));
      const float mnew = fmaxf(m_, tmax);
      const float corr = exp2f(m_ - mnew);
      float ls = 0.f;
      unsigned int pw[4][2];
#pragma unroll
      for (int bb = 0; bb < 4; ++bb) {
        float p0 = exp2f(sv[bb][0] - mnew), p1 = exp2f(sv[bb][1] - mnew);
        float p2 = exp2f(sv[bb][2] - mnew), p3 = exp2f(sv[bb][3] - mnew);
        ls += (p0 + p1) + (p2 + p3);
        pw[bb][0] = (unsigned int)(unsigned short)f2bf(p0) |
                    ((unsigned int)(unsigned short)f2bf(p1) << 16);
        pw[bb][1] = (unsigned int)(unsigned short)f2bf(p2) |
                    ((unsigned int)(unsigned short)f2bf(p3) << 16);
      }
      ls += __shfl_xor(ls, 16);
      ls += __shfl_xor(ls, 32);
      l_ = l_ * corr + ls;
      m_ = mnew;

#pragma unroll
      for (int bb = 0; bb < 4; ++bb)
        *(uint2*)(myP + qi * 128 + ((32 * bb + 8 * g) ^ swz)) =
            make_uint2(pw[bb][0], pw[bb][1]);

      float cr[4];
#pragma unroll
      for (int r = 0; r < 4; ++r) cr[r] = __shfl(corr, 4 * g + r);
#pragma unroll
      for (int j = 0; j < 4; ++j) {
        acc[j][0] *= cr[0]; acc[j][1] *= cr[1];
        acc[j][2] *= cr[2]; acc[j][3] *= cr[3];
      }

      bf16x8 pa0 = *(bf16x8*)(myP + qi * 128 + ((16 * g) ^ swz));
      bf16x8 pa1 = *(bf16x8*)(myP + qi * 128 + ((64 + 16 * g) ^ swz));
#pragma unroll
      for (int j = 0; j < 4; ++j) {
        acc[j] = mfma16(pa0, vf[j][0], acc[j]);
        acc[j] = mfma16(pa1, vf[j][1], acc[j]);
      }
      cur ^= 1;
    }

    const float inv = 1.f / l_;
    float ir[4];
#pragma unroll
    for (int r = 0; r < 4; ++r) ir[r] = __shfl(inv, 4 * g + r);
#pragma unroll
    for (int j = 0; j < 4; ++j)
#pragma unroll
      for (int r = 0; r < 4; ++r)
        AOs[((size_t)b * Sq + q0w + 4 * g + r) * Dm + h * DK + 16 * j + qi] =
            f2bf(acc[j][r] * ir[r]);
  };

  run_chunk(31 - pair);  // big chunk first
  run_chunk(pair);
}

// ================================ launch ===================================
extern "C" void kernel_launch(void* const* d_in, const int* in_sizes, int n_in,
                              void* d_out, int out_size, void* d_ws,
                              size_t ws_size, hipStream_t stream) {
  const float* x  = (const float*)d_in[0];
  const float* Wq = (const float*)d_in[1];
  const float* Wk = (const float*)d_in[2];
  const float* Wv = (const float*)d_in[3];
  const float* Wo = (const float*)d_in[4];
  float* out = (float*)d_out;

  char* w = (char*)d_ws;
  __bf16* Qb  = (__bf16*)(w);                 // 8 MB [bh][s][64]
  __bf16* Kb  = (__bf16*)(w + (8u << 20));    // 8 MB
  __bf16* Vt  = (__bf16*)(w + (16u << 20));   // 8 MB [bh][64][s]
  __bf16* AOb = (__bf16*)(w + (24u << 20));   // 8 MB [B,S,D]
  __bf16* xb  = (__bf16*)(w + (32u << 20));   // 8 MB [4096][1024]
  __bf16* Wt  = (__bf16*)(w + (40u << 20));   // 4 x 2 MB [n][k]
  float2* tbl = (float2*)(w + (48u << 20));   // 512 KB

  const size_t WSZ = (size_t)Dm * Dm;
  conv_x_kernel<<<2048, 256, 0, stream>>>(x, xb);
  conv_wt_kernel<<<dim3(32, 32, 4), 256, 0, stream>>>(Wq, Wk, Wv, Wo, Wt);
  rope_tbl_kernel<<<256, 256, 0, stream>>>(tbl);

  dim3 gg(Dm / 128, Mrows / 128);
  gemm_bf16<0><<<gg, 256, 0, stream>>>(xb, Wt + 0 * WSZ, tbl, (void*)Qb);
  gemm_bf16<0><<<gg, 256, 0, stream>>>(xb, Wt + 1 * WSZ, tbl, (void*)Kb);
  gemm_bf16<1><<<gg, 256, 0, stream>>>(xb, Wt + 2 * WSZ, nullptr, (void*)Vt);
  attn_kernel<<<512, 256, 0, stream>>>(Qb, Kb, Vt, AOb);
  gemm_bf16<2><<<gg, 256, 0, stream>>>(AOb, Wt + 3 * WSZ, nullptr, (void*)out);
}

// Round 7
// 132.211 us; speedup vs baseline: 13.4852x; 1.3515x over previous
//
#include <hip/hip_runtime.h>
#include <cmath>

// ---------------------------------------------------------------------------
// MHA forward, bf16-MFMA everywhere.
//   prep (1 kernel): x->bf16 ; W* -> bf16 transposed [n][k] ; RoPE table
//   gemm_qkv (z=3): xb@Wt -> RoPE(-scaled Q)/RoPE K/V-transpose epilogues
//   attn: causal flash attn (mfma 16x16x32 bf16), XCD-partitioned, paired
//         q-chunks, LDS double-buffered K/V, deferred-max softmax (log2 dom.)
//   gemm_o: AOb@Wto -> out fp32
// B=2 S=2048 D=1024 H=16 dk=64
// ---------------------------------------------------------------------------

constexpr int Bz = 2, Sq = 2048, Dm = 1024, Hh = 16, DK = 64;
constexpr int Mrows = Bz * Sq;  // 4096

typedef __attribute__((ext_vector_type(4))) float f32x4;
typedef __attribute__((ext_vector_type(2))) __bf16 bf16x2;
typedef __attribute__((ext_vector_type(4))) __bf16 bf16x4;
typedef __attribute__((ext_vector_type(8))) __bf16 bf16x8;
typedef __attribute__((ext_vector_type(8))) short short8v;

__device__ __forceinline__ f32x4 mfma16(bf16x8 a, bf16x8 b, f32x4 c) {
  return __builtin_amdgcn_mfma_f32_16x16x32_bf16(a, b, c, 0, 0, 0);
}
__device__ __forceinline__ short bfb(float x) {
  return __builtin_bit_cast(short, (__bf16)x);
}
// async global->LDS, 16 B per lane; lds ptr must be wave-uniform
__device__ __forceinline__ void gload16(const void* g, void* l) {
  __builtin_amdgcn_global_load_lds(
      (__attribute__((address_space(1))) void*)g,
      (__attribute__((address_space(3))) void*)l, 16, 0, 0);
}

// ============================ prep (fused) =================================
// blocks [0,2048): x->bf16 ; [2048,6144): W transpose ; [6144,6400): RoPE tbl
__global__ __launch_bounds__(256) void prep_kernel(
    const float* __restrict__ x, const float* __restrict__ Wq,
    const float* __restrict__ Wk, const float* __restrict__ Wv,
    const float* __restrict__ Wo, __bf16* __restrict__ xb,
    __bf16* __restrict__ Wt, float2* __restrict__ tbl) {
  __shared__ float tile[32][33];
  const int bid = blockIdx.x, tid = threadIdx.x;
  if (bid < 2048) {
    int t = bid * 256 + tid;
    const float4* p = (const float4*)x + (size_t)t * 2;
    float4 a = p[0], b = p[1];
    bf16x8 o = {(__bf16)a.x, (__bf16)a.y, (__bf16)a.z, (__bf16)a.w,
                (__bf16)b.x, (__bf16)b.y, (__bf16)b.z, (__bf16)b.w};
    *(bf16x8*)(xb + (size_t)t * 8) = o;
  } else if (bid < 6144) {
    int wid = bid - 2048;
    int z = wid >> 10, rem = wid & 1023;
    const float* W = (z == 0) ? Wq : (z == 1) ? Wk : (z == 2) ? Wv : Wo;
    __bf16* out = Wt + (size_t)z * Dm * Dm;
    int r0 = (rem >> 5) * 32, c0 = (rem & 31) * 32;
    int r = tid >> 3, c4 = (tid & 7) * 4;
    float4 v = *(const float4*)&W[(size_t)(r0 + r) * Dm + c0 + c4];
    tile[r][c4] = v.x; tile[r][c4 + 1] = v.y;
    tile[r][c4 + 2] = v.z; tile[r][c4 + 3] = v.w;
    __syncthreads();
    int nl = tid >> 3, k4 = (tid & 7) * 4;
    bf16x4 o = {(__bf16)tile[k4][nl], (__bf16)tile[k4 + 1][nl],
                (__bf16)tile[k4 + 2][nl], (__bf16)tile[k4 + 3][nl]};
    *(bf16x4*)&out[(size_t)(c0 + nl) * Dm + r0 + k4] = o;
  } else {
    int t = (bid - 6144) * 256 + tid;  // 65536
    int s = t >> 5, j = t & 31;
    float inv = exp2f(-13.287712379549449f * (1.0f / 32.0f) * (float)j);
    float sn, cs;
    sincosf((float)s * inv, &sn, &cs);
    tbl[t] = make_float2(cs, sn);
  }
}

// ========================= bf16 MFMA GEMM core =============================
// acc[4][4] = A[m0..+128][:] @ Bt[n0..+128][:]^T, BK=32, 4 waves, 16x16x32.
__device__ __forceinline__ void gemm_core(const __bf16* __restrict__ A,
                                          const __bf16* __restrict__ Bt,
                                          char* smem, f32x4 (&acc)[4][4],
                                          int m0, int n0, int tid) {
  short* As = (short*)smem;            // [128][32]
  short* Bs = (short*)(smem + 8192);   // [128][32]
  const int lane = tid & 63, w = tid >> 6;
  const int qi = lane & 15, c = lane >> 4;
  const int wr = w >> 1, wc = w & 1;
  const int srow = lane >> 2, scol = (lane & 3) * 8;
  const __bf16* gA = A + (size_t)(m0 + w * 16 + srow) * Dm + scol;
  const __bf16* gB = Bt + (size_t)(n0 + w * 16 + srow) * Dm + scol;
  short* lA = As + w * 512;  // wave-uniform LDS dest
  short* lB = Bs + w * 512;

#pragma unroll
  for (int i = 0; i < 4; ++i)
#pragma unroll
    for (int j = 0; j < 4; ++j) acc[i][j] = (f32x4){0.f, 0.f, 0.f, 0.f};

  for (int k0 = 0; k0 < Dm; k0 += 32) {
    if (k0) __syncthreads();
    gload16(gA + k0, lA);
    gload16(gA + (size_t)64 * Dm + k0, lA + 2048);
    gload16(gB + k0, lB);
    gload16(gB + (size_t)64 * Dm + k0, lB + 2048);
    __syncthreads();
    bf16x8 af[4], bfv[4];
#pragma unroll
    for (int i = 0; i < 4; ++i) {
      af[i]  = *(bf16x8*)(As + (wr * 64 + i * 16 + qi) * 32 + c * 8);
      bfv[i] = *(bf16x8*)(Bs + (wc * 64 + i * 16 + qi) * 32 + c * 8);
    }
#pragma unroll
    for (int i = 0; i < 4; ++i)
#pragma unroll
      for (int j = 0; j < 4; ++j) acc[i][j] = mfma16(af[i], bfv[j], acc[i][j]);
  }
}

// ===================== fused QKV GEMM (z = 0,1,2) ==========================
// z==0: Q head-layout + RoPE, scaled by 0.125*log2(e).  z==1: K + RoPE.
// z==2: V transposed [bh][d][s].
__global__ __launch_bounds__(256) void gemm_qkv(
    const __bf16* __restrict__ xb, const __bf16* __restrict__ Wt,
    const float2* __restrict__ tbl, __bf16* __restrict__ Qb,
    __bf16* __restrict__ Kb, __bf16* __restrict__ Vt) {
  __shared__ __align__(16) char smem[34816];
  const int tid = threadIdx.x;
  const int z = blockIdx.z;
  const int m0 = blockIdx.y * 128, n0 = blockIdx.x * 128;
  f32x4 acc[4][4];
  gemm_core(xb, Wt + (size_t)z * Dm * Dm, smem, acc, m0, n0, tid);

  const int lane = tid & 63, w = tid >> 6;
  const int qi = lane & 15, c = lane >> 4;
  const int wr = w >> 1, wc = w & 1;

  if (z == 2) {  // Vt[bh][d][s]
    __syncthreads();
    short* T = (short*)smem;  // [128][136] padded
#pragma unroll
    for (int i = 0; i < 4; ++i)
#pragma unroll
      for (int j = 0; j < 4; ++j) {
        int nl = wc * 64 + j * 16 + qi;
        int mb = wr * 64 + i * 16 + c * 4;
        bf16x4 pk = {(__bf16)acc[i][j][0], (__bf16)acc[i][j][1],
                     (__bf16)acc[i][j][2], (__bf16)acc[i][j][3]};
        *(bf16x4*)(T + nl * 136 + mb) = pk;
      }
    __syncthreads();
    short* C = (short*)Vt;
    int b = m0 >> 11, sb = m0 & (Sq - 1);
#pragma unroll
    for (int it = 0; it < 8; ++it) {
      int f = tid + it * 256;
      int nl = f >> 4, mc = f & 15;
      short8v v = *(short8v*)(T + nl * 136 + mc * 8);
      int ng = n0 + nl;
      int d = ng & (DK - 1), h = (ng >> 6) & (Hh - 1);
      *(short8v*)(C + ((size_t)(b * Hh + h) * DK + d) * Sq + sb + mc * 8) = v;
    }
  } else {  // Q or K: head layout + interleaved RoPE
    const float sc = (z == 0) ? 0.18033688011112042f : 1.0f;  // 0.125*log2e
    short* C = (short*)((z == 0) ? Qb : Kb);
#pragma unroll
    for (int j = 0; j < 4; ++j) {
      int n = n0 + wc * 64 + j * 16 + qi;
      int d = n & (DK - 1), h = n >> 6, jj = d >> 1;
#pragma unroll
      for (int i = 0; i < 4; ++i)
#pragma unroll
        for (int r = 0; r < 4; ++r) {
          int m = m0 + wr * 64 + i * 16 + c * 4 + r;
          int s = m & (Sq - 1), b = m >> 11;
          float v = acc[i][j][r];
          float p = __shfl_xor(v, 1);
          float2 t = tbl[s * 32 + jj];
          float o = (qi & 1) ? v * t.x + p * t.y : v * t.x - p * t.y;
          C[((size_t)(b * Hh + h) * Sq + s) * DK + d] = bfb(o * sc);
        }
    }
  }
}

// ============================== O GEMM =====================================
__global__ __launch_bounds__(256) void gemm_o(
    const __bf16* __restrict__ AOb, const __bf16* __restrict__ Wto,
    float* __restrict__ C) {
  __shared__ __align__(16) char smem[34816];
  const int tid = threadIdx.x;
  const int m0 = blockIdx.y * 128, n0 = blockIdx.x * 128;
  f32x4 acc[4][4];
  gemm_core(AOb, Wto, smem, acc, m0, n0, tid);

  const int lane = tid & 63, w = tid >> 6;
  const int qi = lane & 15, c = lane >> 4;
  const int wr = w >> 1, wc = w & 1;
#pragma unroll
  for (int i = 0; i < 4; ++i)
#pragma unroll
    for (int j = 0; j < 4; ++j) {
      int n = n0 + wc * 64 + j * 16 + qi;
#pragma unroll
      for (int r = 0; r < 4; ++r) {
        int m = m0 + wr * 64 + i * 16 + c * 4 + r;
        C[(size_t)m * Dm + n] = acc[i][j][r];
      }
    }
}

// ======================= Flash attention (bf16 MFMA) ========================
// 512 blocks x 4 waves. Block -> (bh, paired q-chunks): uniform 33 tiles.
// XCD-partitioned (bid&7 -> 4 heads). K/V LDS double-buffer via swizzled-
// source global_load_lds. Scores arrive pre-scaled in log2 domain (Q folded).
// Deferred-max online softmax (THR=7 in log2 domain).
__global__ __launch_bounds__(256) void attn_kernel(
    const __bf16* __restrict__ Qb, const __bf16* __restrict__ Kb,
    const __bf16* __restrict__ Vt, __bf16* __restrict__ AOb) {
  // LDS: K[2][8KB] V[2][8KB] P[4][2KB] = 40960 B
  __shared__ __align__(16) char smem[40960];

  const int bid = blockIdx.x;            // 512
  const int xcd = bid & 7;               // hw round-robin -> XCD id (heuristic)
  const int idx = bid >> 3;              // 0..63 within XCD
  const int bh = (xcd << 2) | (idx >> 4);
  const int pair = idx & 15;             // qcA = 31-pair, qcB = pair
  const int b = bh >> 4, h = bh & (Hh - 1);
  const int tid = threadIdx.x, lane = tid & 63, wave = tid >> 6;
  const int g = lane >> 4, qi = lane & 15;

  const __bf16* Qp = Qb + (size_t)bh * Sq * DK;
  const __bf16* Kp = Kb + (size_t)bh * Sq * DK;
  const __bf16* Vp = Vt + (size_t)bh * DK * Sq;

  char* myP = smem + 32768 + wave * 2048;
  const int swz = (qi & 7) << 4;

  const int srow8 = lane >> 3;           // staging row within 8-row segment
  const int scol16 = lane & 7;           // col16 within 128B row
  short* AOs = (short*)AOb;

  auto stage = [&](int cb, int kt) {
    const int kbase = kt * 64;
    char* Kd = smem + cb * 8192;
    char* Vd = smem + 16384 + cb * 8192;
#pragma unroll
    for (int s2 = 0; s2 < 2; ++s2) {
      int seg = wave * 2 + s2;
      int r = seg * 8 + srow8;                       // 0..63
      int csrc = ((scol16 ^ (r & 7)) << 3);          // swizzled source col
      gload16(Kp + (size_t)(kbase + r) * DK + csrc, Kd + seg * 1024);
      gload16(Vp + (size_t)r * Sq + kbase + csrc, Vd + seg * 1024);
    }
  };

  auto run_chunk = [&](int qc) {
    const int q0w = qc * 64 + wave * 16;
    const int nt = qc + 1;

    const bf16x8 qf0 = *(const bf16x8*)(Qp + (q0w + qi) * DK + 8 * g);
    const bf16x8 qf1 = *(const bf16x8*)(Qp + (q0w + qi) * DK + 32 + 8 * g);

    f32x4 acc[4];
#pragma unroll
    for (int j = 0; j < 4; ++j) acc[j] = (f32x4){0.f, 0.f, 0.f, 0.f};
    float m_ = -1e30f, l_ = 0.f;

    __syncthreads();  // protect buffers from previous chunk's readers
    stage(0, 0);

    int cur = 0;
    for (int kt = 0; kt < nt; ++kt) {
      __syncthreads();  // buf[cur] staged (drains vmcnt on all waves)
      if (kt + 1 < nt) stage(cur ^ 1, kt + 1);

      const char* Kt = smem + cur * 8192;
      const char* Vv = smem + 16384 + cur * 8192;
      const int kbase = kt * 64;

      bf16x8 kf[4][2];
#pragma unroll
      for (int bb = 0; bb < 4; ++bb) {
        int rr = 16 * bb + qi;
        kf[bb][0] = *(const bf16x8*)(Kt + rr * 128 + ((g ^ (rr & 7)) << 4));
        kf[bb][1] = *(const bf16x8*)(Kt + rr * 128 + (((g + 4) ^ (rr & 7)) << 4));
      }

      f32x4 st[4];
#pragma unroll
      for (int bb = 0; bb < 4; ++bb) {
        st[bb] = mfma16(kf[bb][0], qf0, (f32x4){0.f, 0.f, 0.f, 0.f});
        st[bb] = mfma16(kf[bb][1], qf1, st[bb]);
      }

      bf16x8 vf[4][2];
#pragma unroll
      for (int j = 0; j < 4; ++j) {
        int rr = 16 * j + qi;
        vf[j][0] = *(const bf16x8*)(Vv + rr * 128 + ((g ^ (rr & 7)) << 4));
        vf[j][1] = *(const bf16x8*)(Vv + rr * 128 + (((g + 4) ^ (rr & 7)) << 4));
      }

      // scores already in log2 domain (scale folded into Q)
      float sv[4][4];
      float tmax = -1e30f;
      const bool maskt = (kt == qc);
#pragma unroll
      for (int bb = 0; bb < 4; ++bb)
#pragma unroll
        for (int r = 0; r < 4; ++r) {
          float v = st[bb][r];
          if (maskt && (kbase + 16 * bb + 4 * g + r > q0w + qi)) v = -1e30f;
          sv[bb][r] = v;
          tmax = fmaxf(tmax, v);
        }
      tmax = fmaxf(tmax, __shfl_xor(tmax, 16));
      tmax = fmaxf(tmax, __shfl_xor(tmax, 32));

      // deferred-max: rescale only when the running max grew by > 7 (log2)
      if (!__all(tmax <= m_ + 7.0f)) {
        const float mnew = fmaxf(m_, tmax);
        const float corr = exp2f(m_ - mnew);
        l_ *= corr;
        float cr[4];
#pragma unroll
        for (int r = 0; r < 4; ++r) cr[r] = __shfl(corr, 4 * g + r);
#pragma unroll
        for (int j = 0; j < 4; ++j) {
          acc[j][0] *= cr[0]; acc[j][1] *= cr[1];
          acc[j][2] *= cr[2]; acc[j][3] *= cr[3];
        }
        m_ = mnew;
      }

      float ls = 0.f;
      unsigned int pw[4][2];
#pragma unroll
      for (int bb = 0; bb < 4; ++bb) {
        float p0 = exp2f(sv[bb][0] - m_), p1 = exp2f(sv[bb][1] - m_);
        float p2 = exp2f(sv[bb][2] - m_), p3 = exp2f(sv[bb][3] - m_);
        ls += (p0 + p1) + (p2 + p3);
        bf16x2 w0 = {(__bf16)p0, (__bf16)p1};
        bf16x2 w1 = {(__bf16)p2, (__bf16)p3};
        pw[bb][0] = __builtin_bit_cast(unsigned int, w0);
        pw[bb][1] = __builtin_bit_cast(unsigned int, w1);
      }
      ls += __shfl_xor(ls, 16);
      ls += __shfl_xor(ls, 32);
      l_ += ls;

#pragma unroll
      for (int bb = 0; bb < 4; ++bb)
        *(uint2*)(myP + qi * 128 + ((32 * bb + 8 * g) ^ swz)) =
            make_uint2(pw[bb][0], pw[bb][1]);

      bf16x8 pa0 = *(bf16x8*)(myP + qi * 128 + ((16 * g) ^ swz));
      bf16x8 pa1 = *(bf16x8*)(myP + qi * 128 + ((64 + 16 * g) ^ swz));
#pragma unroll
      for (int j = 0; j < 4; ++j) {
        acc[j] = mfma16(pa0, vf[j][0], acc[j]);
        acc[j] = mfma16(pa1, vf[j][1], acc[j]);
      }
      cur ^= 1;
    }

    const float inv = 1.f / l_;
    float ir[4];
#pragma unroll
    for (int r = 0; r < 4; ++r) ir[r] = __shfl(inv, 4 * g + r);
#pragma unroll
    for (int j = 0; j < 4; ++j)
#pragma unroll
      for (int r = 0; r < 4; ++r)
        AOs[((size_t)b * Sq + q0w + 4 * g + r) * Dm + h * DK + 16 * j + qi] =
            bfb(acc[j][r] * ir[r]);
  };

  run_chunk(31 - pair);  // big chunk first
  run_chunk(pair);
}

// ================================ launch ===================================
extern "C" void kernel_launch(void* const* d_in, const int* in_sizes, int n_in,
                              void* d_out, int out_size, void* d_ws,
                              size_t ws_size, hipStream_t stream) {
  const float* x  = (const float*)d_in[0];
  const float* Wq = (const float*)d_in[1];
  const float* Wk = (const float*)d_in[2];
  const float* Wv = (const float*)d_in[3];
  const float* Wo = (const float*)d_in[4];
  float* out = (float*)d_out;

  char* w = (char*)d_ws;
  __bf16* Qb  = (__bf16*)(w);                 // 8 MB [bh][s][64] (pre-scaled)
  __bf16* Kb  = (__bf16*)(w + (8u << 20));    // 8 MB
  __bf16* Vt  = (__bf16*)(w + (16u << 20));   // 8 MB [bh][64][s]
  __bf16* AOb = (__bf16*)(w + (24u << 20));   // 8 MB [B,S,D]
  __bf16* xb  = (__bf16*)(w + (32u << 20));   // 8 MB [4096][1024]
  __bf16* Wt  = (__bf16*)(w + (40u << 20));   // 4 x 2 MB [n][k]
  float2* tbl = (float2*)(w + (48u << 20));   // 512 KB

  prep_kernel<<<6400, 256, 0, stream>>>(x, Wq, Wk, Wv, Wo, xb, Wt, tbl);
  gemm_qkv<<<dim3(Dm / 128, Mrows / 128, 3), 256, 0, stream>>>(
      xb, Wt, tbl, Qb, Kb, Vt);
  attn_kernel<<<512, 256, 0, stream>>>(Qb, Kb, Vt, AOb);
  gemm_o<<<dim3(Dm / 128, Mrows / 128), 256, 0, stream>>>(
      AOb, Wt + (size_t)3 * Dm * Dm, out);
}

// Round 8
// 126.581 us; speedup vs baseline: 14.0850x; 1.0445x over previous
//
#include <hip/hip_runtime.h>
#include <cmath>

// ---------------------------------------------------------------------------
// MHA forward, bf16-MFMA everywhere.
//   prep (1 kernel): x->bf16 ; W* -> bf16 transposed [n][k] ; RoPE table
//   gemm_qkv (768 blk, XCD m-band swizzled): xb@Wt -> Q/K (RoPE via LDS
//       transpose epilogue, coalesced) / V-transpose epilogue
//   attn: causal flash attn, XCD-partitioned, paired q-chunks, LDS dbuf K/V,
//         deferred-max softmax in log2 domain
//   gemm_o (256 blk, swizzled): AOb@Wto -> out fp32 (LDS fp32 2-pass epilogue)
// B=2 S=2048 D=1024 H=16 dk=64
// ---------------------------------------------------------------------------

constexpr int Bz = 2, Sq = 2048, Dm = 1024, Hh = 16, DK = 64;
constexpr int Mrows = Bz * Sq;  // 4096

typedef __attribute__((ext_vector_type(4))) float f32x4;
typedef __attribute__((ext_vector_type(2))) __bf16 bf16x2;
typedef __attribute__((ext_vector_type(4))) __bf16 bf16x4;
typedef __attribute__((ext_vector_type(8))) __bf16 bf16x8;
typedef __attribute__((ext_vector_type(8))) short short8v;

__device__ __forceinline__ f32x4 mfma16(bf16x8 a, bf16x8 b, f32x4 c) {
  return __builtin_amdgcn_mfma_f32_16x16x32_bf16(a, b, c, 0, 0, 0);
}
__device__ __forceinline__ short bfb(float x) {
  return __builtin_bit_cast(short, (__bf16)x);
}
// async global->LDS, 16 B per lane; lds ptr must be wave-uniform
__device__ __forceinline__ void gload16(const void* g, void* l) {
  __builtin_amdgcn_global_load_lds(
      (__attribute__((address_space(1))) void*)g,
      (__attribute__((address_space(3))) void*)l, 16, 0, 0);
}

// ============================ prep (fused) =================================
// blocks [0,2048): x->bf16 ; [2048,6144): W transpose ; [6144,6400): RoPE tbl
__global__ __launch_bounds__(256) void prep_kernel(
    const float* __restrict__ x, const float* __restrict__ Wq,
    const float* __restrict__ Wk, const float* __restrict__ Wv,
    const float* __restrict__ Wo, __bf16* __restrict__ xb,
    __bf16* __restrict__ Wt, float2* __restrict__ tbl) {
  __shared__ float tile[32][33];
  const int bid = blockIdx.x, tid = threadIdx.x;
  if (bid < 2048) {
    int t = bid * 256 + tid;
    const float4* p = (const float4*)x + (size_t)t * 2;
    float4 a = p[0], b = p[1];
    bf16x8 o = {(__bf16)a.x, (__bf16)a.y, (__bf16)a.z, (__bf16)a.w,
                (__bf16)b.x, (__bf16)b.y, (__bf16)b.z, (__bf16)b.w};
    *(bf16x8*)(xb + (size_t)t * 8) = o;
  } else if (bid < 6144) {
    int wid = bid - 2048;
    int z = wid >> 10, rem = wid & 1023;
    const float* W = (z == 0) ? Wq : (z == 1) ? Wk : (z == 2) ? Wv : Wo;
    __bf16* out = Wt + (size_t)z * Dm * Dm;
    int r0 = (rem >> 5) * 32, c0 = (rem & 31) * 32;
    int r = tid >> 3, c4 = (tid & 7) * 4;
    float4 v = *(const float4*)&W[(size_t)(r0 + r) * Dm + c0 + c4];
    tile[r][c4] = v.x; tile[r][c4 + 1] = v.y;
    tile[r][c4 + 2] = v.z; tile[r][c4 + 3] = v.w;
    __syncthreads();
    int nl = tid >> 3, k4 = (tid & 7) * 4;
    bf16x4 o = {(__bf16)tile[k4][nl], (__bf16)tile[k4 + 1][nl],
                (__bf16)tile[k4 + 2][nl], (__bf16)tile[k4 + 3][nl]};
    *(bf16x4*)&out[(size_t)(c0 + nl) * Dm + r0 + k4] = o;
  } else {
    int t = (bid - 6144) * 256 + tid;  // 65536
    int s = t >> 5, j = t & 31;
    float inv = exp2f(-13.287712379549449f * (1.0f / 32.0f) * (float)j);
    float sn, cs;
    sincosf((float)s * inv, &sn, &cs);
    tbl[t] = make_float2(cs, sn);
  }
}

// ========================= bf16 MFMA GEMM core =============================
// acc[4][4] = A[m0..+128][:] @ Bt[n0..+128][:]^T, BK=32, 4 waves, 16x16x32.
__device__ __forceinline__ void gemm_core(const __bf16* __restrict__ A,
                                          const __bf16* __restrict__ Bt,
                                          char* smem, f32x4 (&acc)[4][4],
                                          int m0, int n0, int tid) {
  short* As = (short*)smem;            // [128][32]
  short* Bs = (short*)(smem + 8192);   // [128][32]
  const int lane = tid & 63, w = tid >> 6;
  const int qi = lane & 15, c = lane >> 4;
  const int wr = w >> 1, wc = w & 1;
  const int srow = lane >> 2, scol = (lane & 3) * 8;
  const __bf16* gA = A + (size_t)(m0 + w * 16 + srow) * Dm + scol;
  const __bf16* gB = Bt + (size_t)(n0 + w * 16 + srow) * Dm + scol;
  short* lA = As + w * 512;  // wave-uniform LDS dest
  short* lB = Bs + w * 512;

#pragma unroll
  for (int i = 0; i < 4; ++i)
#pragma unroll
    for (int j = 0; j < 4; ++j) acc[i][j] = (f32x4){0.f, 0.f, 0.f, 0.f};

  for (int k0 = 0; k0 < Dm; k0 += 32) {
    if (k0) __syncthreads();
    gload16(gA + k0, lA);
    gload16(gA + (size_t)64 * Dm + k0, lA + 2048);
    gload16(gB + k0, lB);
    gload16(gB + (size_t)64 * Dm + k0, lB + 2048);
    __syncthreads();
    bf16x8 af[4], bfv[4];
#pragma unroll
    for (int i = 0; i < 4; ++i) {
      af[i]  = *(bf16x8*)(As + (wr * 64 + i * 16 + qi) * 32 + c * 8);
      bfv[i] = *(bf16x8*)(Bs + (wc * 64 + i * 16 + qi) * 32 + c * 8);
    }
#pragma unroll
    for (int i = 0; i < 4; ++i)
#pragma unroll
      for (int j = 0; j < 4; ++j) acc[i][j] = mfma16(af[i], bfv[j], acc[i][j]);
  }
}

// ===================== fused QKV GEMM (flattened grid) =====================
// 768 blocks. XCD m-band swizzle: xcd=bid&7 owns m-blocks 4*xcd..+3; within
// XCD order is m-inner so B tiles get back-to-back L2 reuse.
// z==0: Q + RoPE (scaled 0.125*log2e). z==1: K + RoPE. z==2: Vt[bh][d][s].
__global__ __launch_bounds__(256) void gemm_qkv(
    const __bf16* __restrict__ xb, const __bf16* __restrict__ Wt,
    const float2* __restrict__ tbl, __bf16* __restrict__ Qb,
    __bf16* __restrict__ Kb, __bf16* __restrict__ Vt) {
  __shared__ __align__(16) char smem[34816];
  const int tid = threadIdx.x;
  const int bid = blockIdx.x;
  const int xcd = bid & 7, r8 = bid >> 3;          // r8 in [0,96)
  const int mb = (xcd << 2) | (r8 & 3);            // m-block 0..31
  const int zn = r8 >> 2;                          // 0..23
  const int z = zn >> 3, nb = zn & 7;
  const int m0 = mb * 128, n0 = nb * 128;

  f32x4 acc[4][4];
  gemm_core(xb, Wt + (size_t)z * Dm * Dm, smem, acc, m0, n0, tid);

  const int lane = tid & 63, w = tid >> 6;
  const int qi = lane & 15, c = lane >> 4;
  const int wr = w >> 1, wc = w & 1;

  if (z == 2) {  // Vt[bh][d][s]
    __syncthreads();
    short* T = (short*)smem;  // [128][136] padded
#pragma unroll
    for (int i = 0; i < 4; ++i)
#pragma unroll
      for (int j = 0; j < 4; ++j) {
        int nl = wc * 64 + j * 16 + qi;
        int mbr = wr * 64 + i * 16 + c * 4;
        bf16x4 pk = {(__bf16)acc[i][j][0], (__bf16)acc[i][j][1],
                     (__bf16)acc[i][j][2], (__bf16)acc[i][j][3]};
        *(bf16x4*)(T + nl * 136 + mbr) = pk;
      }
    __syncthreads();
    short* C = (short*)Vt;
    int b = m0 >> 11, sb = m0 & (Sq - 1);
#pragma unroll
    for (int it = 0; it < 8; ++it) {
      int f = tid + it * 256;
      int nl = f >> 4, mc = f & 15;
      short8v v = *(short8v*)(T + nl * 136 + mc * 8);
      int ng = n0 + nl;
      int d = ng & (DK - 1), h = (ng >> 6) & (Hh - 1);
      *(short8v*)(C + ((size_t)(b * Hh + h) * DK + d) * Sq + sb + mc * 8) = v;
    }
  } else {  // Q or K: stage raw bf16, RoPE on re-read (pairs in-thread)
    __syncthreads();
    short* T = (short*)smem;  // [128][136]
#pragma unroll
    for (int i = 0; i < 4; ++i)
#pragma unroll
      for (int j = 0; j < 4; ++j) {
        int nl = wc * 64 + j * 16 + qi;
        int mbr = wr * 64 + i * 16 + c * 4;
#pragma unroll
        for (int rr = 0; rr < 4; ++rr)
          T[(mbr + rr) * 136 + nl] = bfb(acc[i][j][rr]);
      }
    __syncthreads();
    const float sc = (z == 0) ? 0.18033688011112042f : 1.0f;  // 0.125*log2e
    short* C = (short*)((z == 0) ? Qb : Kb);
    const int b = m0 >> 11;
#pragma unroll
    for (int it = 0; it < 8; ++it) {
      int f = tid + it * 256;
      int ml = f >> 4, c16 = f & 15;
      bf16x8 v = *(bf16x8*)(T + ml * 136 + c16 * 8);
      int s = (m0 + ml) & (Sq - 1);
      int n = n0 + c16 * 8;
      int d0 = n & (DK - 1), h = (n >> 6) & (Hh - 1);
      int jj = d0 >> 1;
      float4 t01 = *(const float4*)&tbl[s * 32 + jj];      // cos0,sin0,cos1,sin1
      float4 t23 = *(const float4*)&tbl[s * 32 + jj + 2];
      bf16x8 o;
      float x0 = (float)v[0], y0 = (float)v[1];
      o[0] = (__bf16)((x0 * t01.x - y0 * t01.y) * sc);
      o[1] = (__bf16)((y0 * t01.x + x0 * t01.y) * sc);
      float x1 = (float)v[2], y1 = (float)v[3];
      o[2] = (__bf16)((x1 * t01.z - y1 * t01.w) * sc);
      o[3] = (__bf16)((y1 * t01.z + x1 * t01.w) * sc);
      float x2 = (float)v[4], y2 = (float)v[5];
      o[4] = (__bf16)((x2 * t23.x - y2 * t23.y) * sc);
      o[5] = (__bf16)((y2 * t23.x + x2 * t23.y) * sc);
      float x3 = (float)v[6], y3 = (float)v[7];
      o[6] = (__bf16)((x3 * t23.z - y3 * t23.w) * sc);
      o[7] = (__bf16)((y3 * t23.z + x3 * t23.w) * sc);
      *(bf16x8*)(C + ((size_t)(b * Hh + h) * Sq + s) * DK + d0) = o;
    }
  }
}

// ============================== O GEMM =====================================
// 256 blocks, XCD m-band swizzle. fp32 output via 2-pass LDS transpose.
__global__ __launch_bounds__(256) void gemm_o(
    const __bf16* __restrict__ AOb, const __bf16* __restrict__ Wto,
    float* __restrict__ C) {
  __shared__ __align__(16) char smem[34816];
  const int tid = threadIdx.x;
  const int bid = blockIdx.x;
  const int xcd = bid & 7, r8 = bid >> 3;          // r8 in [0,32)
  const int mb = (xcd << 2) | (r8 & 3);
  const int nb = r8 >> 2;
  const int m0 = mb * 128, n0 = nb * 128;

  f32x4 acc[4][4];
  gemm_core(AOb, Wto, smem, acc, m0, n0, tid);

  const int lane = tid & 63, w = tid >> 6;
  const int qi = lane & 15, c = lane >> 4;
  const int wr = w >> 1, wc = w & 1;
  float* T32 = (float*)smem;  // [64][132] = 33792 B

#pragma unroll
  for (int pass = 0; pass < 2; ++pass) {
    __syncthreads();
#pragma unroll
    for (int i2 = 0; i2 < 2; ++i2) {
      int i = pass * 2 + i2;
#pragma unroll
      for (int j = 0; j < 4; ++j) {
        int nl = wc * 64 + j * 16 + qi;
        int cm = wr * 32 + i2 * 16 + c * 4;
#pragma unroll
        for (int rr = 0; rr < 4; ++rr)
          T32[(cm + rr) * 132 + nl] = acc[i][j][rr];
      }
    }
    __syncthreads();
#pragma unroll
    for (int it = 0; it < 8; ++it) {
      int f = tid + it * 256;           // 0..2047
      int cm = f >> 5, c4 = f & 31;
      float4 v = *(float4*)(T32 + cm * 132 + c4 * 4);
      int m = m0 + (cm >> 5) * 64 + pass * 32 + (cm & 31);
      *(float4*)&C[(size_t)m * Dm + n0 + c4 * 4] = v;
    }
  }
}

// ======================= Flash attention (bf16 MFMA) ========================
// 512 blocks x 4 waves. Block -> (bh, paired q-chunks): uniform 33 tiles.
// XCD-partitioned (bid&7 -> 4 heads). K/V LDS double-buffer via swizzled-
// source global_load_lds. Scores arrive pre-scaled in log2 domain (Q folded).
// Deferred-max online softmax (THR=7 in log2 domain).
__global__ __launch_bounds__(256) void attn_kernel(
    const __bf16* __restrict__ Qb, const __bf16* __restrict__ Kb,
    const __bf16* __restrict__ Vt, __bf16* __restrict__ AOb) {
  // LDS: K[2][8KB] V[2][8KB] P[4][2KB] = 40960 B
  __shared__ __align__(16) char smem[40960];

  const int bid = blockIdx.x;            // 512
  const int xcd = bid & 7;               // hw round-robin -> XCD id (heuristic)
  const int idx = bid >> 3;              // 0..63 within XCD
  const int bh = (xcd << 2) | (idx >> 4);
  const int pair = idx & 15;             // qcA = 31-pair, qcB = pair
  const int b = bh >> 4, h = bh & (Hh - 1);
  const int tid = threadIdx.x, lane = tid & 63, wave = tid >> 6;
  const int g = lane >> 4, qi = lane & 15;

  const __bf16* Qp = Qb + (size_t)bh * Sq * DK;
  const __bf16* Kp = Kb + (size_t)bh * Sq * DK;
  const __bf16* Vp = Vt + (size_t)bh * DK * Sq;

  char* myP = smem + 32768 + wave * 2048;
  const int swz = (qi & 7) << 4;

  const int srow8 = lane >> 3;           // staging row within 8-row segment
  const int scol16 = lane & 7;           // col16 within 128B row
  short* AOs = (short*)AOb;

  auto stage = [&](int cb, int kt) {
    const int kbase = kt * 64;
    char* Kd = smem + cb * 8192;
    char* Vd = smem + 16384 + cb * 8192;
#pragma unroll
    for (int s2 = 0; s2 < 2; ++s2) {
      int seg = wave * 2 + s2;
      int r = seg * 8 + srow8;                       // 0..63
      int csrc = ((scol16 ^ (r & 7)) << 3);          // swizzled source col
      gload16(Kp + (size_t)(kbase + r) * DK + csrc, Kd + seg * 1024);
      gload16(Vp + (size_t)r * Sq + kbase + csrc, Vd + seg * 1024);
    }
  };

  auto run_chunk = [&](int qc) {
    const int q0w = qc * 64 + wave * 16;
    const int nt = qc + 1;

    const bf16x8 qf0 = *(const bf16x8*)(Qp + (q0w + qi) * DK + 8 * g);
    const bf16x8 qf1 = *(const bf16x8*)(Qp + (q0w + qi) * DK + 32 + 8 * g);

    f32x4 acc[4];
#pragma unroll
    for (int j = 0; j < 4; ++j) acc[j] = (f32x4){0.f, 0.f, 0.f, 0.f};
    float m_ = -1e30f, l_ = 0.f;

    __syncthreads();  // protect buffers from previous chunk's readers
    stage(0, 0);

    int cur = 0;
    for (int kt = 0; kt < nt; ++kt) {
      __syncthreads();  // buf[cur] staged (drains vmcnt on all waves)
      if (kt + 1 < nt) stage(cur ^ 1, kt + 1);

      const char* Kt = smem + cur * 8192;
      const char* Vv = smem + 16384 + cur * 8192;
      const int kbase = kt * 64;

      bf16x8 kf[4][2];
#pragma unroll
      for (int bb = 0; bb < 4; ++bb) {
        int rr = 16 * bb + qi;
        kf[bb][0] = *(const bf16x8*)(Kt + rr * 128 + ((g ^ (rr & 7)) << 4));
        kf[bb][1] = *(const bf16x8*)(Kt + rr * 128 + (((g + 4) ^ (rr & 7)) << 4));
      }

      f32x4 st[4];
#pragma unroll
      for (int bb = 0; bb < 4; ++bb) {
        st[bb] = mfma16(kf[bb][0], qf0, (f32x4){0.f, 0.f, 0.f, 0.f});
        st[bb] = mfma16(kf[bb][1], qf1, st[bb]);
      }

      bf16x8 vf[4][2];
#pragma unroll
      for (int j = 0; j < 4; ++j) {
        int rr = 16 * j + qi;
        vf[j][0] = *(const bf16x8*)(Vv + rr * 128 + ((g ^ (rr & 7)) << 4));
        vf[j][1] = *(const bf16x8*)(Vv + rr * 128 + (((g + 4) ^ (rr & 7)) << 4));
      }

      // scores already in log2 domain (scale folded into Q)
      float sv[4][4];
      float tmax = -1e30f;
      const bool maskt = (kt == qc);
#pragma unroll
      for (int bb = 0; bb < 4; ++bb)
#pragma unroll
        for (int r = 0; r < 4; ++r) {
          float v = st[bb][r];
          if (maskt && (kbase + 16 * bb + 4 * g + r > q0w + qi)) v = -1e30f;
          sv[bb][r] = v;
          tmax = fmaxf(tmax, v);
        }
      tmax = fmaxf(tmax, __shfl_xor(tmax, 16));
      tmax = fmaxf(tmax, __shfl_xor(tmax, 32));

      // deferred-max: rescale only when the running max grew by > 7 (log2)
      if (!__all(tmax <= m_ + 7.0f)) {
        const float mnew = fmaxf(m_, tmax);
        const float corr = exp2f(m_ - mnew);
        l_ *= corr;
        float cr[4];
#pragma unroll
        for (int r = 0; r < 4; ++r) cr[r] = __shfl(corr, 4 * g + r);
#pragma unroll
        for (int j = 0; j < 4; ++j) {
          acc[j][0] *= cr[0]; acc[j][1] *= cr[1];
          acc[j][2] *= cr[2]; acc[j][3] *= cr[3];
        }
        m_ = mnew;
      }

      float ls = 0.f;
      unsigned int pw[4][2];
#pragma unroll
      for (int bb = 0; bb < 4; ++bb) {
        float p0 = exp2f(sv[bb][0] - m_), p1 = exp2f(sv[bb][1] - m_);
        float p2 = exp2f(sv[bb][2] - m_), p3 = exp2f(sv[bb][3] - m_);
        ls += (p0 + p1) + (p2 + p3);
        bf16x2 w0 = {(__bf16)p0, (__bf16)p1};
        bf16x2 w1 = {(__bf16)p2, (__bf16)p3};
        pw[bb][0] = __builtin_bit_cast(unsigned int, w0);
        pw[bb][1] = __builtin_bit_cast(unsigned int, w1);
      }
      ls += __shfl_xor(ls, 16);
      ls += __shfl_xor(ls, 32);
      l_ += ls;

#pragma unroll
      for (int bb = 0; bb < 4; ++bb)
        *(uint2*)(myP + qi * 128 + ((32 * bb + 8 * g) ^ swz)) =
            make_uint2(pw[bb][0], pw[bb][1]);

      bf16x8 pa0 = *(bf16x8*)(myP + qi * 128 + ((16 * g) ^ swz));
      bf16x8 pa1 = *(bf16x8*)(myP + qi * 128 + ((64 + 16 * g) ^ swz));
#pragma unroll
      for (int j = 0; j < 4; ++j) {
        acc[j] = mfma16(pa0, vf[j][0], acc[j]);
        acc[j] = mfma16(pa1, vf[j][1], acc[j]);
      }
      cur ^= 1;
    }

    const float inv = 1.f / l_;
    float ir[4];
#pragma unroll
    for (int r = 0; r < 4; ++r) ir[r] = __shfl(inv, 4 * g + r);
#pragma unroll
    for (int j = 0; j < 4; ++j)
#pragma unroll
      for (int r = 0; r < 4; ++r)
        AOs[((size_t)b * Sq + q0w + 4 * g + r) * Dm + h * DK + 16 * j + qi] =
            bfb(acc[j][r] * ir[r]);
  };

  run_chunk(31 - pair);  // big chunk first
  run_chunk(pair);
}

// ================================ launch ===================================
extern "C" void kernel_launch(void* const* d_in, const int* in_sizes, int n_in,
                              void* d_out, int out_size, void* d_ws,
                              size_t ws_size, hipStream_t stream) {
  const float* x  = (const float*)d_in[0];
  const float* Wq = (const float*)d_in[1];
  const float* Wk = (const float*)d_in[2];
  const float* Wv = (const float*)d_in[3];
  const float* Wo = (const float*)d_in[4];
  float* out = (float*)d_out;

  char* w = (char*)d_ws;
  __bf16* Qb  = (__bf16*)(w);                 // 8 MB [bh][s][64] (pre-scaled)
  __bf16* Kb  = (__bf16*)(w + (8u << 20));    // 8 MB
  __bf16* Vt  = (__bf16*)(w + (16u << 20));   // 8 MB [bh][64][s]
  __bf16* AOb = (__bf16*)(w + (24u << 20));   // 8 MB [B,S,D]
  __bf16* xb  = (__bf16*)(w + (32u << 20));   // 8 MB [4096][1024]
  __bf16* Wt  = (__bf16*)(w + (40u << 20));   // 4 x 2 MB [n][k]
  float2* tbl = (float2*)(w + (48u << 20));   // 512 KB

  prep_kernel<<<6400, 256, 0, stream>>>(x, Wq, Wk, Wv, Wo, xb, Wt, tbl);
  gemm_qkv<<<768, 256, 0, stream>>>(xb, Wt, tbl, Qb, Kb, Vt);
  attn_kernel<<<512, 256, 0, stream>>>(Qb, Kb, Vt, AOb);
  gemm_o<<<256, 256, 0, stream>>>(AOb, Wt + (size_t)3 * Dm * Dm, out);
}